// Round 5
// baseline (378.145 us; speedup 1.0000x reference)
//
#include <hip/hip_runtime.h>
#include <math.h>

constexpr int Nn = 50000;
constexpr int Ee = 10000;
constexpr int Ll = 50;
constexpr int LuU = 20;
constexpr int Dd = 128;
constexpr int Bb = 512;
constexpr int TVv = 768;
constexpr int Dw = 130;
constexpr int BL = Bb * Ll;     // 25600 (unpadded rows)
constexpr int BLP = Bb * 64;    // 32768 (padded rows per branch)

typedef __attribute__((ext_vector_type(8))) short bf8v;
typedef __attribute__((ext_vector_type(4))) float f4v;
typedef __attribute__((ext_vector_type(8))) unsigned short u16x8;
typedef __attribute__((ext_vector_type(4))) unsigned short u16x4;

__device__ __forceinline__ unsigned short f2bf(float f) {
  union { float f; unsigned u; } v; v.f = f;
  unsigned r = v.u + 0x7FFFu + ((v.u >> 16) & 1u);
  return (unsigned short)(r >> 16);
}
__device__ __forceinline__ float bf2f(unsigned short h) {
  union { unsigned u; float f; } v; v.u = ((unsigned)h) << 16; return v.f;
}
// XOR swizzle for [rows][256B] tiles: 16B slot ^= row&7
__device__ __forceinline__ int swz(int b) { return b ^ (((b >> 8) & 7) << 4); }
// XOR swizzle for [rows][128B] tiles: 16B slot ^= row&7 (8 slots)
__device__ __forceinline__ int swz7(int b) { return b ^ (((b >> 7) & 7) << 4); }

// ---------------- block reduction ----------------
__device__ __forceinline__ float block_sum_256(float v, volatile float* scr) {
#pragma unroll
  for (int o = 32; o > 0; o >>= 1) v += __shfl_down(v, o, 64);
  __syncthreads();
  if ((threadIdx.x & 63) == 0) scr[threadIdx.x >> 6] = v;
  __syncthreads();
  return scr[0] + scr[1] + scr[2] + scr[3];
}

// ---------------- cosine / inter_nw ----------------
__global__ __launch_bounds__(256) void k_cos(const float* __restrict__ w3,
                                             float* __restrict__ dotb,
                                             float* __restrict__ nrmb) {
  __shared__ float scr[4];
  int i = blockIdx.x;
  const float* row = w3 + (size_t)i * TVv;
  float d = 0.f, n = 0.f;
  for (int j = threadIdx.x; j < TVv; j += 256) {
    float a = row[j];
    d += a * w3[j];
    n += a * a;
  }
  d = block_sum_256(d, scr);
  n = block_sum_256(n, scr);
  if (threadIdx.x == 0) { dotb[i] = d; nrmb[i] = n; }
}

__global__ __launch_bounds__(256) void k_internw(const float* __restrict__ dotb,
                                                 const float* __restrict__ nrmb,
                                                 float* __restrict__ internw) {
  __shared__ float scr[4];
  float n0 = sqrtf(nrmb[0]);
  float s = 0.f;
  for (int i = threadIdx.x; i < TVv; i += 256)
    s += dotb[i] / (n0 * sqrtf(nrmb[i]));
  s = block_sum_256(s, scr);
  if (threadIdx.x == 0) *internw = s / (float)TVv;
}

// ---------------- weight prep: f32 [k][n] -> bf16 [n][k] ----------------
__global__ __launch_bounds__(256) void k_prep(
    const float* w1, const float* w2,
    const float* twq, const float* twk, const float* twv, const float* two,
    const float* swq, const float* swk, const float* swv, const float* swo,
    unsigned short* __restrict__ out) {
  int wsel = blockIdx.x >> 3, part = blockIdx.x & 7;
  const float* w;
  switch (wsel) {
    case 0: w = w1; break;  case 1: w = w2; break;
    case 2: w = twq; break; case 3: w = twk; break;
    case 4: w = twv; break; case 5: w = two; break;
    case 6: w = swq; break; case 7: w = swk; break;
    case 8: w = swv; break; default: w = swo; break;
  }
  int u = part * 256 + threadIdx.x;
  int n = u >> 4, k0 = (u & 15) * 8;
  u16x8 pv;
#pragma unroll
  for (int i = 0; i < 8; i++) pv[i] = f2bf(w[(size_t)(k0 + i) * Dd + n]);
  ((u16x8*)(out + (size_t)wsel * Dd * Dd))[u] = pv;
}

// ---------------- MFMA GEMM (64-row tile, bf16 out) ----------------
template <int MODE>
__global__ __launch_bounds__(256) void k_gemm_plain(
    const void* __restrict__ inA, const float* __restrict__ in1,
    const int* __restrict__ gidx, const float* __restrict__ scalep,
    const unsigned short* __restrict__ WTg,
    unsigned short* __restrict__ out, int nrows) {
  __shared__ unsigned short WT[Dd * Dd];
  __shared__ __align__(16) unsigned short Ab[64 * Dd];
  int tid = threadIdx.x;
  {
    const u16x8* src = (const u16x8*)WTg;
    for (int u = tid; u < 2048; u += 256)
      *(u16x8*)((char*)WT + swz(u * 16)) = src[u];
  }
  int r0 = blockIdx.x * 64;
  if constexpr (MODE == 0) {
    float sc = *scalep;
    for (int u = tid; u < 1024; u += 256) {
      int rr = u >> 4, c0 = (u & 15) * 8;
      int r = r0 + rr;
      u16x8 pv;
      if (r < nrows) {
        const float* a = (const float*)inA + (size_t)r * Dd + c0;
        const float* c = in1 + (size_t)gidx[r] * Dd + c0;
#pragma unroll
        for (int i = 0; i < 8; i++) pv[i] = f2bf((a[i] + c[i]) * sc);
      } else {
#pragma unroll
        for (int i = 0; i < 8; i++) pv[i] = 0;
      }
      *(u16x8*)((char*)Ab + swz(rr * 256 + c0 * 2)) = pv;
    }
  } else {
    for (int u = tid; u < 1024; u += 256) {
      int rr = u >> 4;
      int r = r0 + rr;
      u16x8 pv;
      if (r < nrows) pv = ((const u16x8*)inA)[(size_t)r * 16 + (u & 15)];
      else {
#pragma unroll
        for (int i = 0; i < 8; i++) pv[i] = 0;
      }
      *(u16x8*)((char*)Ab + swz(rr * 256 + (u & 15) * 16)) = pv;
    }
  }
  __syncthreads();
  int lane = tid & 63, wid = tid >> 6;
  int lrow = lane & 15, lg = lane >> 4;
  bf8v af[4];
#pragma unroll
  for (int kc = 0; kc < 4; kc++)
    af[kc] = *(const bf8v*)((char*)Ab + swz((wid * 16 + lrow) * 256 + kc * 64 + lg * 16));
  f4v acc[8];
#pragma unroll
  for (int nt = 0; nt < 8; nt++)
#pragma unroll
    for (int j = 0; j < 4; j++) acc[nt][j] = 0.f;
#pragma unroll
  for (int nt = 0; nt < 8; nt++)
#pragma unroll
    for (int kc = 0; kc < 4; kc++) {
      bf8v bfg = *(const bf8v*)((char*)WT + swz((nt * 16 + lrow) * 256 + kc * 64 + lg * 16));
      acc[nt] = __builtin_amdgcn_mfma_f32_16x16x32_bf16(af[kc], bfg, acc[nt], 0, 0, 0);
    }
#pragma unroll
  for (int nt = 0; nt < 8; nt++)
#pragma unroll
    for (int j = 0; j < 4; j++) {
      int r = r0 + wid * 16 + lg * 4 + j;
      if (r < nrows) out[(size_t)r * Dd + nt * 16 + lrow] = f2bf(acc[nt][j]);
    }
}

// ---------------- QKV GEMM: 128 padded rows (2 b's), Q/K padded out, V -> VT ----
__global__ __launch_bounds__(256) void k_gemm_qkv(
    const unsigned short* __restrict__ hidT, const unsigned short* __restrict__ hidS,
    const unsigned short* __restrict__ WTbase,
    unsigned short* __restrict__ Qp, unsigned short* __restrict__ Kp,
    unsigned short* __restrict__ VTp) {
  __shared__ unsigned short WT[Dd * Dd];                  // 32 KB
  __shared__ __align__(16) unsigned short Ab[128 * Dd];   // 32 KB (A, then V^T)
  int tile = blockIdx.x & 255, branch = blockIdx.x >> 8;
  const unsigned short* in = branch ? hidS : hidT;
  int tid = threadIdx.x;
  // A stage: padded rows (rr&63 >= 50 -> zero)
  for (int u = tid; u < 2048; u += 256) {
    int rr = u >> 4, ch = u & 15;
    int brow = rr >> 6, sub = rr & 63;
    u16x8 pv;
    if (sub < Ll)
      pv = ((const u16x8*)in)[(size_t)((tile * 2 + brow) * Ll + sub) * 16 + ch];
    else {
#pragma unroll
      for (int i = 0; i < 8; i++) pv[i] = 0;
    }
    *(u16x8*)((char*)Ab + swz(rr * 256 + ch * 16)) = pv;
  }
  {
    const u16x8* srcW = (const u16x8*)(WTbase + (size_t)(2 + branch * 4) * Dd * Dd);
    for (int u = tid; u < 2048; u += 256)
      *(u16x8*)((char*)WT + swz(u * 16)) = srcW[u];
  }
  __syncthreads();
  int lane = tid & 63, wid = tid >> 6;
  int lrow = lane & 15, lg = lane >> 4;
  bf8v af[2][4];
#pragma unroll
  for (int mi = 0; mi < 2; mi++)
#pragma unroll
    for (int kc = 0; kc < 4; kc++)
      af[mi][kc] = *(const bf8v*)((char*)Ab +
                    swz((wid * 32 + mi * 16 + lrow) * 256 + kc * 64 + lg * 16));
#pragma unroll 1
  for (int sel = 0; sel < 3; sel++) {
    f4v acc[2][8];
#pragma unroll
    for (int mi = 0; mi < 2; mi++)
#pragma unroll
      for (int nt = 0; nt < 8; nt++)
#pragma unroll
        for (int j = 0; j < 4; j++) acc[mi][nt][j] = 0.f;
#pragma unroll
    for (int nt = 0; nt < 8; nt++)
#pragma unroll
      for (int kc = 0; kc < 4; kc++) {
        bf8v bfg = *(const bf8v*)((char*)WT + swz((nt * 16 + lrow) * 256 + kc * 64 + lg * 16));
        acc[0][nt] = __builtin_amdgcn_mfma_f32_16x16x32_bf16(af[0][kc], bfg, acc[0][nt], 0, 0, 0);
        acc[1][nt] = __builtin_amdgcn_mfma_f32_16x16x32_bf16(af[1][kc], bfg, acc[1][nt], 0, 0, 0);
      }
    if (sel < 2) {
      unsigned short* outb = ((sel == 0) ? Qp : Kp) + (size_t)branch * BLP * Dd;
#pragma unroll
      for (int mi = 0; mi < 2; mi++)
#pragma unroll
        for (int nt = 0; nt < 8; nt++)
#pragma unroll
          for (int j = 0; j < 4; j++) {
            int r = tile * 128 + wid * 32 + mi * 16 + lg * 4 + j;
            outb[(size_t)r * Dd + nt * 16 + lrow] = f2bf(acc[mi][nt][j]);
          }
      __syncthreads();
      const u16x8* srcW = (const u16x8*)(WTbase + (size_t)(2 + branch * 4 + sel + 1) * Dd * Dd);
      for (int u = tid; u < 2048; u += 256)
        *(u16x8*)((char*)WT + swz(u * 16)) = srcW[u];
      __syncthreads();
    } else {
      // V: transpose via LDS (reuse Ab as [128 d][128 r] bf16, swizzled)
      __syncthreads();
#pragma unroll
      for (int mi = 0; mi < 2; mi++)
#pragma unroll
        for (int nt = 0; nt < 8; nt++) {
          int d = nt * 16 + lrow;
          int rl = wid * 32 + mi * 16 + lg * 4;
          u16x4 tv;
#pragma unroll
          for (int j = 0; j < 4; j++) tv[j] = f2bf(acc[mi][nt][j]);
          *(u16x4*)((char*)Ab + swz(d * 256 + rl * 2)) = tv;
        }
      __syncthreads();
      for (int u = tid; u < 2048; u += 256) {
        int d = u >> 4, ch = u & 15;
        u16x8 pv = *(const u16x8*)((char*)Ab + swz(d * 256 + ch * 16));
        int bidx = ch >> 3, kv0 = (ch & 7) * 8;
        *(u16x8*)(VTp + (((size_t)branch * Bb + tile * 2 + bidx) * Dd + d) * 64 + kv0) = pv;
      }
    }
  }
}

// ---------------- MFMA GEMM + residual + LayerNorm (padded ctx in) --------------
__global__ __launch_bounds__(256) void k_gemm_ln(
    const unsigned short* __restrict__ ctxp,
    const unsigned short* __restrict__ hidT, const unsigned short* __restrict__ hidS,
    const unsigned short* __restrict__ WTbase,
    const float* __restrict__ tg, const float* __restrict__ tb,
    const float* __restrict__ sg, const float* __restrict__ sb_,
    unsigned short* __restrict__ attall) {
  __shared__ unsigned short WT[Dd * Dd];
  __shared__ __align__(16) char UB[64 * 132 * 4];
  unsigned short* Ab = (unsigned short*)UB;
  float (*O)[132] = (float (*)[132])UB;

  int b = blockIdx.x & 511, branch = blockIdx.x >> 9;
  const unsigned short* resid = (branch ? hidS : hidT);
  const unsigned short* Wg = WTbase + (size_t)(5 + branch * 4) * Dd * Dd;
  const float* lng = branch ? sg : tg;
  const float* lnb = branch ? sb_ : tb;
  unsigned short* out = attall + (size_t)branch * BL * Dd;
  int tid = threadIdx.x;

  {
    const u16x8* src = (const u16x8*)Wg;
    for (int u = tid; u < 2048; u += 256)
      *(u16x8*)((char*)WT + swz(u * 16)) = src[u];
  }
  for (int u = tid; u < 1024; u += 256) {
    int rr = u >> 4;
    u16x8 pv = ((const u16x8*)ctxp)[(((size_t)branch * Bb + b) * 64 + rr) * 16 + (u & 15)];
    *(u16x8*)((char*)Ab + swz(rr * 256 + (u & 15) * 16)) = pv;
  }
  __syncthreads();

  int lane = tid & 63, wid = tid >> 6;
  int lrow = lane & 15, lg = lane >> 4;
  bf8v af[4];
#pragma unroll
  for (int kc = 0; kc < 4; kc++)
    af[kc] = *(const bf8v*)((char*)Ab + swz((wid * 16 + lrow) * 256 + kc * 64 + lg * 16));
  f4v acc[8];
#pragma unroll
  for (int nt = 0; nt < 8; nt++)
#pragma unroll
    for (int j = 0; j < 4; j++) acc[nt][j] = 0.f;
#pragma unroll
  for (int nt = 0; nt < 8; nt++)
#pragma unroll
    for (int kc = 0; kc < 4; kc++) {
      bf8v bfg = *(const bf8v*)((char*)WT + swz((nt * 16 + lrow) * 256 + kc * 64 + lg * 16));
      acc[nt] = __builtin_amdgcn_mfma_f32_16x16x32_bf16(af[kc], bfg, acc[nt], 0, 0, 0);
    }
  __syncthreads();
#pragma unroll
  for (int nt = 0; nt < 8; nt++)
#pragma unroll
    for (int j = 0; j < 4; j++)
      O[wid * 16 + lg * 4 + j][nt * 16 + lrow] = acc[nt][j];
  __syncthreads();
  int r = tid >> 2, c0 = (tid & 3) * 32;
  if (r < Ll) {
    size_t gr = (size_t)b * Ll + r;
    float vv[32];
    float s1 = 0.f, s2 = 0.f;
#pragma unroll
    for (int i8 = 0; i8 < 4; i8++) {
      u16x8 hb = *(const u16x8*)(resid + gr * Dd + c0 + i8 * 8);
#pragma unroll
      for (int i = 0; i < 8; i++) {
        float x = O[r][c0 + i8 * 8 + i] + bf2f(hb[i]);
        vv[i8 * 8 + i] = x; s1 += x; s2 += x * x;
      }
    }
    s1 += __shfl_xor(s1, 1, 64); s2 += __shfl_xor(s2, 1, 64);
    s1 += __shfl_xor(s1, 2, 64); s2 += __shfl_xor(s2, 2, 64);
    float mu = s1 * (1.f / Dd);
    float var = s2 * (1.f / Dd) - mu * mu;
    float rs = rsqrtf(var + 1e-6f);
#pragma unroll
    for (int i8 = 0; i8 < 4; i8++) {
      u16x8 ov;
#pragma unroll
      for (int i = 0; i < 8; i++) {
        int c = c0 + i8 * 8 + i;
        ov[i] = f2bf((vv[i8 * 8 + i] - mu) * rs * lng[c] + lnb[c]);
      }
      *(u16x8*)(out + gr * Dd + c0 + i8 * 8) = ov;
    }
  }
}

// ---------------- edge gather ----------------
__global__ __launch_bounds__(256) void k_gather_e(const unsigned short* __restrict__ X,
                                                  const int* __restrict__ seq,
                                                  unsigned short* __restrict__ EDGE) {
  int r = blockIdx.x * 16 + (threadIdx.x >> 4);
  int c0 = (threadIdx.x & 15) * 8;
  const int* row = seq + (size_t)r * Ll;
  float acc[8];
#pragma unroll
  for (int i = 0; i < 8; i++) acc[i] = 0.f;
  int cnt = 0;
#pragma unroll 1
  for (int l0 = 0; l0 < Ll; l0 += 10) {
    int ids[10];
#pragma unroll
    for (int t = 0; t < 10; t++) ids[t] = row[l0 + t];
    u16x8 vv[10];
#pragma unroll
    for (int t = 0; t < 10; t++)
      vv[t] = *(const u16x8*)(X + (size_t)ids[t] * Dd + c0);
#pragma unroll
    for (int t = 0; t < 10; t++)
      if (ids[t] > 0) {
        cnt++;
#pragma unroll
        for (int i = 0; i < 8; i++) acc[i] += bf2f(vv[t][i]);
      }
  }
  u16x8 ov;
  if (cnt) {
    float inv = 1.f / (float)cnt;
#pragma unroll
    for (int i = 0; i < 8; i++) ov[i] = f2bf(fmaxf(acc[i] * inv, 0.f));
  } else {
    u16x8 x0 = *(const u16x8*)(X + c0);
#pragma unroll
    for (int i = 0; i < 8; i++) ov[i] = f2bf(fmaxf(bf2f(x0[i]), 0.f));
  }
  *(u16x8*)(EDGE + (size_t)r * Dd + c0) = ov;
}

// ---------------- fused node-gather + hidden build ----------------
__global__ __launch_bounds__(256) void k_hidfuse(
    const unsigned short* __restrict__ E1, const int* __restrict__ data_idx,
    const int* __restrict__ seq, const int* __restrict__ tsmp,
    const int* __restrict__ uinf, const int* __restrict__ ulev,
    const int* __restrict__ useq,
    const float* __restrict__ time_emb, const float* __restrict__ inf_emb,
    const float* __restrict__ pos_emb,
    unsigned short* __restrict__ hidTb, unsigned short* __restrict__ hidSb) {
  int bl = blockIdx.x * 16 + (threadIdx.x >> 4);
  int c0 = (threadIdx.x & 15) * 8;
  int b = bl / Ll, l = bl % Ll;
  int e = data_idx[b];
  int sid = seq[(size_t)e * Ll + l];
  const int* urow = useq + (size_t)sid * LuU;
  float acc[8];
#pragma unroll
  for (int i = 0; i < 8; i++) acc[i] = 0.f;
  int cnt = 0;
#pragma unroll 1
  for (int t0 = 0; t0 < LuU; t0 += 10) {
    int ids[10];
#pragma unroll
    for (int t = 0; t < 10; t++) ids[t] = urow[t0 + t];
    u16x8 vv[10];
#pragma unroll
    for (int t = 0; t < 10; t++)
      vv[t] = *(const u16x8*)(E1 + (size_t)ids[t] * Dd + c0);
#pragma unroll
    for (int t = 0; t < 10; t++)
      if (ids[t] > 0) {
        cnt++;
#pragma unroll
        for (int i = 0; i < 8; i++) acc[i] += bf2f(vv[t][i]);
      }
  }
  float node[8];
  if (cnt) {
    float inv = 1.f / (float)cnt;
#pragma unroll
    for (int i = 0; i < 8; i++) node[i] = acc[i] * inv;
  } else {
    u16x8 e0 = *(const u16x8*)(E1 + c0);
#pragma unroll
    for (int i = 0; i < 8; i++) node[i] = bf2f(e0[i]);
  }
  int ts = tsmp[(size_t)e * Ll + l];
  int fi = uinf[(size_t)e * Ll + l];
  int lv = ulev[(size_t)e * Ll + l];
  const float4* tp = (const float4*)(time_emb + (size_t)ts * Dd + c0);
  const float4* ip = (const float4*)(inf_emb + (size_t)fi * Dd + c0);
  const float4* pp = (const float4*)(pos_emb + (size_t)lv * Dd + c0);
  float4 t0 = tp[0], t1 = tp[1];
  float4 i0 = ip[0], i1 = ip[1];
  float4 p0 = pp[0], p1 = pp[1];
  float te[8] = {t0.x, t0.y, t0.z, t0.w, t1.x, t1.y, t1.z, t1.w};
  float ie[8] = {i0.x, i0.y, i0.z, i0.w, i1.x, i1.y, i1.z, i1.w};
  float pe[8] = {p0.x, p0.y, p0.z, p0.w, p1.x, p1.y, p1.z, p1.w};
  u16x8 ht, hs;
#pragma unroll
  for (int i = 0; i < 8; i++) {
    ht[i] = f2bf(node[i] + te[i]);
    hs[i] = f2bf(node[i] + ie[i] + pe[i]);
  }
  size_t o = (size_t)bl * Dd + c0;
  *(u16x8*)(hidTb + o) = ht;
  *(u16x8*)(hidSb + o) = hs;
}

// ---------------- MFMA attention: block=(branch,b), wave=2 heads, reg-direct ----
__global__ __launch_bounds__(256, 4) void k_attn_mfma(
    const unsigned short* __restrict__ Qp,
    const unsigned short* __restrict__ Kp,
    const unsigned short* __restrict__ VTp,
    const int* __restrict__ data_idx,
    const int* __restrict__ seq,
    unsigned short* __restrict__ ctxp) {
  __shared__ __align__(16) char PTs[4 * 8192];   // per-wave P^T [64 q][128B kv]
  __shared__ int maskl[Ll];
  int b = blockIdx.x, branch = blockIdx.y;
  int tid = threadIdx.x, lane = tid & 63, wid = tid >> 6;
  if (tid < Ll) maskl[tid] = (seq[(size_t)data_idx[b] * Ll + tid] == 0);
  __syncthreads();
  int lrow = lane & 15, lg = lane >> 4;
  size_t rbase = ((size_t)branch * Bb + b) * 64;    // padded row base (Q/K/ctx)
  size_t vrow  = ((size_t)branch * Bb + b) * Dd;    // VT d-row base
  char* PTw = PTs + wid * 8192;
#pragma unroll 1
  for (int hi = 0; hi < 2; hi++) {
    int h = wid * 2 + hi;
    // ---- S^T = K_h @ Q_h^T: fragments straight from global ----
    bf8v af[4], bq[4];
    if (lg < 2) {
#pragma unroll
      for (int t = 0; t < 4; t++) {
        af[t] = *(const bf8v*)(Kp + (rbase + t * 16 + lrow) * Dd + h * 16 + lg * 8);
        bq[t] = *(const bf8v*)(Qp + (rbase + t * 16 + lrow) * Dd + h * 16 + lg * 8);
      }
    } else {
#pragma unroll
      for (int t = 0; t < 4; t++)
#pragma unroll
        for (int i = 0; i < 8; i++) { af[t][i] = 0; bq[t][i] = 0; }
    }
#pragma unroll 1
    for (int nt = 0; nt < 4; nt++) {
      f4v sa[4];
#pragma unroll
      for (int mt = 0; mt < 4; mt++)
#pragma unroll
        for (int j = 0; j < 4; j++) sa[mt][j] = 0.f;
#pragma unroll
      for (int mt = 0; mt < 4; mt++)
        sa[mt] = __builtin_amdgcn_mfma_f32_16x16x32_bf16(af[mt], bq[nt], sa[mt], 0, 0, 0);
      float m = -3.0e38f;
#pragma unroll
      for (int mt = 0; mt < 4; mt++)
#pragma unroll
        for (int j = 0; j < 4; j++) {
          int kk = mt * 16 + lg * 4 + j;
          int mk = (kk < Ll) ? maskl[kk] : 2;        // 2 => pad
          float v = sa[mt][j] * 0.25f;
          v = (mk == 1) ? -1e9f : v;
          v = (mk == 2) ? -3.0e38f : v;
          sa[mt][j] = v;
          m = fmaxf(m, v);
        }
      m = fmaxf(m, __shfl_xor(m, 16, 64));
      m = fmaxf(m, __shfl_xor(m, 32, 64));
      float s = 0.f;
#pragma unroll
      for (int mt = 0; mt < 4; mt++)
#pragma unroll
        for (int j = 0; j < 4; j++) {
          float p = expf(sa[mt][j] - m);
          sa[mt][j] = p;
          s += p;
        }
      s += __shfl_xor(s, 16, 64);
      s += __shfl_xor(s, 32, 64);
      float inv = 1.f / s;
      int q = nt * 16 + lrow;
#pragma unroll
      for (int mt = 0; mt < 4; mt++) {
        u16x4 pw;
#pragma unroll
        for (int j = 0; j < 4; j++) pw[j] = f2bf(sa[mt][j] * inv);
        *(u16x4*)(PTw + swz7(q * 128 + mt * 32 + lg * 8)) = pw;
      }
    }
    // ---- O^T = V_h^T @ P^T: A-frag from VT global, B-frag from PT LDS ----
    f4v pacc[4];
#pragma unroll
    for (int nt = 0; nt < 4; nt++)
#pragma unroll
      for (int j = 0; j < 4; j++) pacc[nt][j] = 0.f;
#pragma unroll
    for (int kt = 0; kt < 2; kt++) {
      bf8v av = *(const bf8v*)(VTp + (vrow + h * 16 + lrow) * 64 + kt * 32 + lg * 8);
#pragma unroll
      for (int nt = 0; nt < 4; nt++) {
        bf8v bv = *(const bf8v*)(PTw + swz7((nt * 16 + lrow) * 128 + kt * 64 + lg * 16));
        pacc[nt] = __builtin_amdgcn_mfma_f32_16x16x32_bf16(av, bv, pacc[nt], 0, 0, 0);
      }
    }
    // ---- write ctx (padded; junk rows >=50 are guarded downstream) ----
#pragma unroll
    for (int nt = 0; nt < 4; nt++) {
      int q = nt * 16 + lrow;
      unsigned* cp = (unsigned*)(ctxp + (rbase + q) * Dd + h * 16 + lg * 4);
      cp[0] = (unsigned)f2bf(pacc[nt][0]) | ((unsigned)f2bf(pacc[nt][1]) << 16);
      cp[1] = (unsigned)f2bf(pacc[nt][2]) | ((unsigned)f2bf(pacc[nt][3]) << 16);
    }
  }
}

// ---------------- news weighted reduce ----------------
__global__ __launch_bounds__(128) void k_newsred(const unsigned short* __restrict__ attall,
                                                 const int* __restrict__ data_idx,
                                                 const int* __restrict__ seq,
                                                 const float* __restrict__ spread,
                                                 float* __restrict__ news) {
  __shared__ int sl[Ll];
  __shared__ int scnt;
  int b = blockIdx.x, branch = blockIdx.y;
  int e = data_idx[b];
  const unsigned short* att = attall + (size_t)branch * BL * Dd;
  if (threadIdx.x < Ll) sl[threadIdx.x] = seq[(size_t)e * Ll + threadIdx.x];
  __syncthreads();
  if (threadIdx.x == 0) {
    int c = 0;
    for (int l = 0; l < Ll; l++) c += (sl[l] > 0);
    scnt = c;
  }
  __syncthreads();
  int cnt = scnt;
  float wnp = cnt ? 1.f / (float)cnt : 0.02f;
  int c = threadIdx.x;
  float acc = 0.f;
  for (int l = 0; l < Ll; l++) {
    float w = cnt ? ((sl[l] > 0) ? wnp : 0.f) : wnp;
    acc += w * bf2f(att[((size_t)b * Ll + l) * Dd + c]);
  }
  float* nrow = news + ((size_t)branch * Bb + b) * 132;
  nrow[c] = acc;
  if (c < 2) {
    nrow[Dd + c] = branch ? spread[(size_t)e * 4 + c]
                          : spread[(size_t)e * 4 + 2 + c] * (1.f / 86400.f);
  }
}

// ---------------- news @ W ----------------
__global__ __launch_bounds__(256) void k_newsW(const float* __restrict__ news,
                                               const float* __restrict__ Wm,
                                               const float* __restrict__ W2m,
                                               float* __restrict__ NT,
                                               float* __restrict__ NS) {
  __shared__ float Wl[Dw][Dw + 1];
  __shared__ float nrow[132];
  int branch = blockIdx.y;
  const float* W = branch ? W2m : Wm;
  float* out = branch ? NS : NT;
  for (int u = threadIdx.x; u < Dw * Dw; u += 256)
    Wl[u / Dw][u % Dw] = W[u];
  for (int rr = 0; rr < 32; rr++) {
    int b = blockIdx.x * 32 + rr;
    __syncthreads();
    if (threadIdx.x < Dw)
      nrow[threadIdx.x] = news[((size_t)branch * Bb + b) * 132 + threadIdx.x];
    __syncthreads();
    int j = threadIdx.x;
    if (j < Dw) {
      float acc = 0.f;
      for (int kk = 0; kk < Dw; kk++) acc += nrow[kk] * Wl[kk][j];
      out[(size_t)b * Dw + j] = acc;
    }
  }
}

// ---------------- gated fusion + classifier + log_softmax ----------------
__global__ __launch_bounds__(256) void k_fusion(const float* __restrict__ nt,
                                                const float* __restrict__ ns,
                                                const float* __restrict__ l1w,
                                                const float* __restrict__ l1b,
                                                const float* __restrict__ l2w,
                                                const float* __restrict__ l2b,
                                                const float* __restrict__ linw,
                                                const float* __restrict__ linb,
                                                float* __restrict__ out) {
  __shared__ float rt[Dw], rs[Dw];
  __shared__ float scr[4];
  int b = blockIdx.x, j = threadIdx.x;
  if (j < Dw) { rt[j] = nt[(size_t)b * Dw + j]; rs[j] = ns[(size_t)b * Dw + j]; }
  __syncthreads();
  float pt = 0.f, ps = 0.f;
  if (j < Dw) {
    float at = l1b[j], as = l1b[j];
    for (int kk = 0; kk < Dw; kk++) {
      float w = l1w[(size_t)kk * Dw + j];
      at += rt[kk] * w;
      as += rs[kk] * w;
    }
    float lw2 = l2w[j];
    pt = tanhf(at) * lw2;
    ps = tanhf(as) * lw2;
  }
  float st = block_sum_256(pt, scr);
  float ss = block_sum_256(ps, scr);
  st += l2b[0]; ss += l2b[0];
  float m = fmaxf(st, ss);
  float e0 = expf(st - m), e1v = expf(ss - m);
  float inv = 1.f / (e0 + e1v);
  float s0 = e0 * inv, s1 = e1v * inv;
  float fj  = (j < Dw) ? (s0 * rt[j] + s1 * rs[j]) : 0.f;
  float w0  = (j < Dw) ? linw[(size_t)j * 2 + 0] : 0.f;
  float w1v = (j < Dw) ? linw[(size_t)j * 2 + 1] : 0.f;
  float l0 = block_sum_256(fj * w0, scr);
  float l1 = block_sum_256(fj * w1v, scr);
  if (j == 0) {
    l0 += linb[0]; l1 += linb[1];
    float mm = fmaxf(l0, l1);
    float lse = mm + logf(expf(l0 - mm) + expf(l1 - mm));
    out[(size_t)b * 2 + 0] = l0 - lse;
    out[(size_t)b * 2 + 1] = l1 - lse;
  }
}

extern "C" void kernel_launch(void* const* d_in, const int* in_sizes, int n_in,
                              void* d_out, int out_size, void* d_ws, size_t ws_size,
                              hipStream_t stream) {
  const int*   data_idx = (const int*)d_in[0];
  const int*   seq      = (const int*)d_in[1];
  const int*   tsmp     = (const int*)d_in[2];
  const int*   ulev     = (const int*)d_in[3];
  const int*   useq     = (const int*)d_in[4];
  const int*   uinf     = (const int*)d_in[5];
  const int*   ucen     = (const int*)d_in[6];
  const float* spread   = (const float*)d_in[7];
  const float* user_emb = (const float*)d_in[9];
  const float* cen_emb  = (const float*)d_in[10];
  const float* time_emb = (const float*)d_in[11];
  const float* pos_emb  = (const float*)d_in[12];
  const float* inf_emb  = (const float*)d_in[13];
  const float* w1       = (const float*)d_in[14];
  const float* w2       = (const float*)d_in[15];
  const float* w3       = (const float*)d_in[16];
  const float* Wm       = (const float*)d_in[17];
  const float* W2m      = (const float*)d_in[18];
  const float* f_l1_w   = (const float*)d_in[19];
  const float* f_l1_b   = (const float*)d_in[20];
  const float* f_l2_w   = (const float*)d_in[21];
  const float* f_l2_b   = (const float*)d_in[22];
  const float* lin_w    = (const float*)d_in[23];
  const float* lin_b    = (const float*)d_in[24];
  const float* t_wq = (const float*)d_in[25];
  const float* t_wk = (const float*)d_in[26];
  const float* t_wv = (const float*)d_in[27];
  const float* t_wo = (const float*)d_in[28];
  const float* t_g  = (const float*)d_in[29];
  const float* t_b  = (const float*)d_in[30];
  const float* s_wq = (const float*)d_in[31];
  const float* s_wk = (const float*)d_in[32];
  const float* s_wv = (const float*)d_in[33];
  const float* s_wo = (const float*)d_in[34];
  const float* s_g  = (const float*)d_in[35];
  const float* s_b  = (const float*)d_in[36];

  char* ws = (char*)d_ws;
  constexpr size_t SZ_WT  = (size_t)10 * Dd * Dd * 2;
  constexpr size_t SZ_XB  = (size_t)Nn * Dd * 2;
  constexpr size_t SZ_EB  = (size_t)Ee * Dd * 2;
  constexpr size_t SZ_BH  = (size_t)BL * Dd * 2;       // unpadded bf16 [BL][128]
  constexpr size_t SZ_PD  = (size_t)2 * BLP * Dd * 2;  // padded 2-branch tensors
  constexpr size_t OFF_WT  = 8192;
  constexpr size_t OFF_X   = OFF_WT + SZ_WT;
  constexpr size_t OFF_EDGE= OFF_X + SZ_XB;
  constexpr size_t OFF_E1  = OFF_EDGE + SZ_EB;
  constexpr size_t OFF_HTB = OFF_E1 + SZ_EB;
  constexpr size_t OFF_HSB = OFF_HTB + SZ_BH;
  constexpr size_t OFF_Q   = OFF_HSB + SZ_BH;
  constexpr size_t OFF_K   = OFF_Q + SZ_PD;
  constexpr size_t OFF_VT  = OFF_K + SZ_PD;
  constexpr size_t OFF_CTX = OFF_VT + SZ_PD;
  constexpr size_t OFF_ATT = OFF_Q;                    // alias: Q dead after attn
  constexpr size_t OFF_NEWS= OFF_CTX + SZ_PD;
  constexpr size_t OFF_NT  = OFF_NEWS + (size_t)2 * Bb * 132 * 4;
  constexpr size_t OFF_NS  = OFF_NT + (size_t)Bb * Dw * 4;

  float* dotb    = (float*)(ws + 0);
  float* nrmb    = (float*)(ws + 3072);
  float* internw = (float*)(ws + 6144);
  unsigned short* WTall = (unsigned short*)(ws + OFF_WT);
  unsigned short* Xb    = (unsigned short*)(ws + OFF_X);
  unsigned short* EDGEb = (unsigned short*)(ws + OFF_EDGE);
  unsigned short* E1b   = (unsigned short*)(ws + OFF_E1);
  unsigned short* HIDTb = (unsigned short*)(ws + OFF_HTB);
  unsigned short* HIDSb = (unsigned short*)(ws + OFF_HSB);
  unsigned short* Qp    = (unsigned short*)(ws + OFF_Q);
  unsigned short* Kp    = (unsigned short*)(ws + OFF_K);
  unsigned short* VTp   = (unsigned short*)(ws + OFF_VT);
  unsigned short* CTXp  = (unsigned short*)(ws + OFF_CTX);
  unsigned short* ATTall= (unsigned short*)(ws + OFF_ATT);
  float*          NEWS  = (float*)(ws + OFF_NEWS);
  float*          NT    = (float*)(ws + OFF_NT);
  float*          NS    = (float*)(ws + OFF_NS);
  float* outp = (float*)d_out;

  k_prep<<<80, 256, 0, stream>>>(w1, w2, t_wq, t_wk, t_wv, t_wo,
                                 s_wq, s_wk, s_wv, s_wo, WTall);
  k_cos<<<TVv, 256, 0, stream>>>(w3, dotb, nrmb);
  k_internw<<<1, 256, 0, stream>>>(dotb, nrmb, internw);

  k_gemm_plain<0><<<(Nn + 63) / 64, 256, 0, stream>>>(
      user_emb, cen_emb, ucen, internw, WTall + 0 * Dd * Dd, Xb, Nn);
  k_gather_e<<<Ee / 16, 256, 0, stream>>>(Xb, seq, EDGEb);
  k_gemm_plain<1><<<(Ee + 63) / 64, 256, 0, stream>>>(
      EDGEb, nullptr, nullptr, nullptr, WTall + 1 * Dd * Dd, E1b, Ee);
  k_hidfuse<<<BL / 16, 256, 0, stream>>>(E1b, data_idx, seq, tsmp, uinf, ulev, useq,
                                         time_emb, inf_emb, pos_emb, HIDTb, HIDSb);

  k_gemm_qkv<<<512, 256, 0, stream>>>(HIDTb, HIDSb, WTall, Qp, Kp, VTp);
  k_attn_mfma<<<dim3(Bb, 2), 256, 0, stream>>>(Qp, Kp, VTp, data_idx, seq, CTXp);
  k_gemm_ln<<<1024, 256, 0, stream>>>(CTXp, HIDTb, HIDSb, WTall,
                                      t_g, t_b, s_g, s_b, ATTall);

  k_newsred<<<dim3(Bb, 2), 128, 0, stream>>>(ATTall, data_idx, seq, spread, NEWS);
  k_newsW<<<dim3(16, 2), 256, 0, stream>>>(NEWS, Wm, W2m, NT, NS);
  k_fusion<<<Bb, 256, 0, stream>>>(NT, NS, f_l1_w, f_l1_b, f_l2_w, f_l2_b,
                                   lin_w, lin_b, outp);

  (void)in_sizes; (void)n_in; (void)out_size; (void)ws_size;
}

// Round 6
// 365.993 us; speedup vs baseline: 1.0332x; 1.0332x over previous
//
#include <hip/hip_runtime.h>
#include <math.h>

constexpr int Nn = 50000;
constexpr int Ee = 10000;
constexpr int Ll = 50;
constexpr int LuU = 20;
constexpr int Dd = 128;
constexpr int Bb = 512;
constexpr int TVv = 768;
constexpr int Dw = 130;
constexpr int BL = Bb * Ll;     // 25600 (unpadded rows)
constexpr int BLP = Bb * 64;    // 32768 (padded rows per branch)

typedef __attribute__((ext_vector_type(8))) short bf8v;
typedef __attribute__((ext_vector_type(4))) float f4v;
typedef __attribute__((ext_vector_type(8))) unsigned short u16x8;
typedef __attribute__((ext_vector_type(4))) unsigned short u16x4;

__device__ __forceinline__ unsigned short f2bf(float f) {
  union { float f; unsigned u; } v; v.f = f;
  unsigned r = v.u + 0x7FFFu + ((v.u >> 16) & 1u);
  return (unsigned short)(r >> 16);
}
__device__ __forceinline__ float bf2f(unsigned short h) {
  union { unsigned u; float f; } v; v.u = ((unsigned)h) << 16; return v.f;
}
// XOR swizzle for [rows][256B] tiles: 16B slot ^= row&7
__device__ __forceinline__ int swz(int b) { return b ^ (((b >> 8) & 7) << 4); }
// XOR swizzle for [rows][128B] tiles: 16B slot ^= row&7
__device__ __forceinline__ int swz7(int b) { return b ^ (((b >> 7) & 7) << 4); }

// ---------------- block reduction ----------------
__device__ __forceinline__ float block_sum_256(float v, volatile float* scr) {
#pragma unroll
  for (int o = 32; o > 0; o >>= 1) v += __shfl_down(v, o, 64);
  __syncthreads();
  if ((threadIdx.x & 63) == 0) scr[threadIdx.x >> 6] = v;
  __syncthreads();
  return scr[0] + scr[1] + scr[2] + scr[3];
}

// ---------------- cosine / inter_nw ----------------
__global__ __launch_bounds__(256) void k_cos(const float* __restrict__ w3,
                                             float* __restrict__ dotb,
                                             float* __restrict__ nrmb) {
  __shared__ float scr[4];
  int i = blockIdx.x;
  const float* row = w3 + (size_t)i * TVv;
  float d = 0.f, n = 0.f;
  for (int j = threadIdx.x; j < TVv; j += 256) {
    float a = row[j];
    d += a * w3[j];
    n += a * a;
  }
  d = block_sum_256(d, scr);
  n = block_sum_256(n, scr);
  if (threadIdx.x == 0) { dotb[i] = d; nrmb[i] = n; }
}

__global__ __launch_bounds__(256) void k_internw(const float* __restrict__ dotb,
                                                 const float* __restrict__ nrmb,
                                                 float* __restrict__ internw) {
  __shared__ float scr[4];
  float n0 = sqrtf(nrmb[0]);
  float s = 0.f;
  for (int i = threadIdx.x; i < TVv; i += 256)
    s += dotb[i] / (n0 * sqrtf(nrmb[i]));
  s = block_sum_256(s, scr);
  if (threadIdx.x == 0) *internw = s / (float)TVv;
}

// ---------------- weight prep: f32 [k][n] -> bf16 [n][k] ----------------
__global__ __launch_bounds__(256) void k_prep(
    const float* w1, const float* w2,
    const float* twq, const float* twk, const float* twv, const float* two,
    const float* swq, const float* swk, const float* swv, const float* swo,
    unsigned short* __restrict__ out) {
  int wsel = blockIdx.x >> 3, part = blockIdx.x & 7;
  const float* w;
  switch (wsel) {
    case 0: w = w1; break;  case 1: w = w2; break;
    case 2: w = twq; break; case 3: w = twk; break;
    case 4: w = twv; break; case 5: w = two; break;
    case 6: w = swq; break; case 7: w = swk; break;
    case 8: w = swv; break; default: w = swo; break;
  }
  int u = part * 256 + threadIdx.x;
  int n = u >> 4, k0 = (u & 15) * 8;
  u16x8 pv;
#pragma unroll
  for (int i = 0; i < 8; i++) pv[i] = f2bf(w[(size_t)(k0 + i) * Dd + n]);
  ((u16x8*)(out + (size_t)wsel * Dd * Dd))[u] = pv;
}

// ---------------- MFMA GEMM (64-row tile, bf16 out) ----------------
template <int MODE>
__global__ __launch_bounds__(256) void k_gemm_plain(
    const void* __restrict__ inA, const float* __restrict__ in1,
    const int* __restrict__ gidx, const float* __restrict__ scalep,
    const unsigned short* __restrict__ WTg,
    unsigned short* __restrict__ out, int nrows) {
  __shared__ unsigned short WT[Dd * Dd];
  __shared__ __align__(16) unsigned short Ab[64 * Dd];
  int tid = threadIdx.x;
  {
    const u16x8* src = (const u16x8*)WTg;
    for (int u = tid; u < 2048; u += 256)
      *(u16x8*)((char*)WT + swz(u * 16)) = src[u];
  }
  int r0 = blockIdx.x * 64;
  if constexpr (MODE == 0) {
    float sc = *scalep;
    for (int u = tid; u < 1024; u += 256) {
      int rr = u >> 4, c0 = (u & 15) * 8;
      int r = r0 + rr;
      u16x8 pv;
      if (r < nrows) {
        const float* a = (const float*)inA + (size_t)r * Dd + c0;
        const float* c = in1 + (size_t)gidx[r] * Dd + c0;
#pragma unroll
        for (int i = 0; i < 8; i++) pv[i] = f2bf((a[i] + c[i]) * sc);
      } else {
#pragma unroll
        for (int i = 0; i < 8; i++) pv[i] = 0;
      }
      *(u16x8*)((char*)Ab + swz(rr * 256 + c0 * 2)) = pv;
    }
  } else {
    for (int u = tid; u < 1024; u += 256) {
      int rr = u >> 4;
      int r = r0 + rr;
      u16x8 pv;
      if (r < nrows) pv = ((const u16x8*)inA)[(size_t)r * 16 + (u & 15)];
      else {
#pragma unroll
        for (int i = 0; i < 8; i++) pv[i] = 0;
      }
      *(u16x8*)((char*)Ab + swz(rr * 256 + (u & 15) * 16)) = pv;
    }
  }
  __syncthreads();
  int lane = tid & 63, wid = tid >> 6;
  int lrow = lane & 15, lg = lane >> 4;
  bf8v af[4];
#pragma unroll
  for (int kc = 0; kc < 4; kc++)
    af[kc] = *(const bf8v*)((char*)Ab + swz((wid * 16 + lrow) * 256 + kc * 64 + lg * 16));
  f4v acc[8];
#pragma unroll
  for (int nt = 0; nt < 8; nt++)
#pragma unroll
    for (int j = 0; j < 4; j++) acc[nt][j] = 0.f;
#pragma unroll
  for (int nt = 0; nt < 8; nt++)
#pragma unroll
    for (int kc = 0; kc < 4; kc++) {
      bf8v bfg = *(const bf8v*)((char*)WT + swz((nt * 16 + lrow) * 256 + kc * 64 + lg * 16));
      acc[nt] = __builtin_amdgcn_mfma_f32_16x16x32_bf16(af[kc], bfg, acc[nt], 0, 0, 0);
    }
#pragma unroll
  for (int nt = 0; nt < 8; nt++)
#pragma unroll
    for (int j = 0; j < 4; j++) {
      int r = r0 + wid * 16 + lg * 4 + j;
      if (r < nrows) out[(size_t)r * Dd + nt * 16 + lrow] = f2bf(acc[nt][j]);
    }
}

// ---------------- fused QKV GEMM + attention: block = (branch, b) ----------------
// LDS (80 KB): AQ 16K (HID->Qs) | WP 32K (Wq/Wk/Wv->PT) | Ks 16K | VTs 16K
__global__ __launch_bounds__(256, 2) void k_qkvattn(
    const unsigned short* __restrict__ hidT, const unsigned short* __restrict__ hidS,
    const unsigned short* __restrict__ WTbase,
    const int* __restrict__ data_idx, const int* __restrict__ seq,
    unsigned short* __restrict__ ctxp) {
  __shared__ __align__(16) char LDS[81920];
  unsigned short* AQ  = (unsigned short*)(LDS);           // HID stage, then Qs[q][d]
  unsigned short* WP  = (unsigned short*)(LDS + 16384);   // W stage, then PT (8K/wave)
  unsigned short* Ks  = (unsigned short*)(LDS + 49152);   // Ks[kv][d]
  unsigned short* VTs = (unsigned short*)(LDS + 65536);   // VTs[d][kv] 128B rows

  int b = blockIdx.x, branch = blockIdx.y;
  int tid = threadIdx.x, lane = tid & 63, wid = tid >> 6;
  int lrow = lane & 15, lg = lane >> 4;
  const unsigned short* hid = (branch ? hidS : hidT) + (size_t)b * Ll * Dd;

  // per-lane key-mask flags via wave shfl: 0 ok, 1 masked, 2 pad
  int e = data_idx[b];
  int mi = (lane < Ll) ? (seq[(size_t)e * Ll + lane] == 0 ? 1 : 0) : 2;
  int mflag[4][4];
#pragma unroll
  for (int mt = 0; mt < 4; mt++)
#pragma unroll
    for (int j = 0; j < 4; j++)
      mflag[mt][j] = __shfl(mi, mt * 16 + lg * 4 + j, 64);

  // stage HID (64 padded rows, swizzled)
  for (int u = tid; u < 1024; u += 256) {
    int rr = u >> 4, ch = u & 15;
    u16x8 pv;
    if (rr < Ll) pv = *(const u16x8*)(hid + (size_t)rr * Dd + ch * 8);
    else {
#pragma unroll
      for (int i = 0; i < 8; i++) pv[i] = 0;
    }
    *(u16x8*)((char*)AQ + swz(rr * 256 + ch * 16)) = pv;
  }
  // stage Wq
  {
    const u16x8* srcW = (const u16x8*)(WTbase + (size_t)(2 + branch * 4) * Dd * Dd);
    for (int u = tid; u < 2048; u += 256)
      *(u16x8*)((char*)WP + swz(u * 16)) = srcW[u];
  }
  __syncthreads();
  // HID fragments for this wave's 16 rows (reused for Q,K as B and V as A)
  bf8v hf[4];
#pragma unroll
  for (int kc = 0; kc < 4; kc++)
    hf[kc] = *(const bf8v*)((char*)AQ + swz((wid * 16 + lrow) * 256 + kc * 64 + lg * 16));
  __syncthreads();     // all hf loaded -> AQ reusable as Qs

  // ---- Q (swapped operands): C[d][q]; write Qs[q][d] with 8B vectors ----
  {
    f4v acc[8];
#pragma unroll
    for (int nt = 0; nt < 8; nt++)
#pragma unroll
      for (int j = 0; j < 4; j++) acc[nt][j] = 0.f;
#pragma unroll
    for (int nt = 0; nt < 8; nt++)
#pragma unroll
      for (int kc = 0; kc < 4; kc++) {
        bf8v wf = *(const bf8v*)((char*)WP + swz((nt * 16 + lrow) * 256 + kc * 64 + lg * 16));
        acc[nt] = __builtin_amdgcn_mfma_f32_16x16x32_bf16(wf, hf[kc], acc[nt], 0, 0, 0);
      }
    __syncthreads();   // all WP (Wq) reads done
#pragma unroll
    for (int nt = 0; nt < 8; nt++) {
      u16x4 qv;
#pragma unroll
      for (int j = 0; j < 4; j++) qv[j] = f2bf(acc[nt][j]);
      *(u16x4*)((char*)AQ + swz((wid * 16 + lrow) * 256 + (nt * 16 + lg * 4) * 2)) = qv;
    }
  }
  // stage Wk
  {
    const u16x8* srcW = (const u16x8*)(WTbase + (size_t)(3 + branch * 4) * Dd * Dd);
    for (int u = tid; u < 2048; u += 256)
      *(u16x8*)((char*)WP + swz(u * 16)) = srcW[u];
  }
  __syncthreads();
  // ---- K (swapped): C[d][kv]; write Ks[kv][d] ----
  {
    f4v acc[8];
#pragma unroll
    for (int nt = 0; nt < 8; nt++)
#pragma unroll
      for (int j = 0; j < 4; j++) acc[nt][j] = 0.f;
#pragma unroll
    for (int nt = 0; nt < 8; nt++)
#pragma unroll
      for (int kc = 0; kc < 4; kc++) {
        bf8v wf = *(const bf8v*)((char*)WP + swz((nt * 16 + lrow) * 256 + kc * 64 + lg * 16));
        acc[nt] = __builtin_amdgcn_mfma_f32_16x16x32_bf16(wf, hf[kc], acc[nt], 0, 0, 0);
      }
    __syncthreads();   // all WP (Wk) reads done
#pragma unroll
    for (int nt = 0; nt < 8; nt++) {
      u16x4 kv4;
#pragma unroll
      for (int j = 0; j < 4; j++) kv4[j] = f2bf(acc[nt][j]);
      *(u16x4*)((char*)Ks + swz((wid * 16 + lrow) * 256 + (nt * 16 + lg * 4) * 2)) = kv4;
    }
  }
  // stage Wv
  {
    const u16x8* srcW = (const u16x8*)(WTbase + (size_t)(4 + branch * 4) * Dd * Dd);
    for (int u = tid; u < 2048; u += 256)
      *(u16x8*)((char*)WP + swz(u * 16)) = srcW[u];
  }
  __syncthreads();
  // ---- V (normal): C[kv][d]; write VTs[d][kv] ----
  {
    f4v acc[8];
#pragma unroll
    for (int nt = 0; nt < 8; nt++)
#pragma unroll
      for (int j = 0; j < 4; j++) acc[nt][j] = 0.f;
#pragma unroll
    for (int nt = 0; nt < 8; nt++)
#pragma unroll
      for (int kc = 0; kc < 4; kc++) {
        bf8v wf = *(const bf8v*)((char*)WP + swz((nt * 16 + lrow) * 256 + kc * 64 + lg * 16));
        acc[nt] = __builtin_amdgcn_mfma_f32_16x16x32_bf16(hf[kc], wf, acc[nt], 0, 0, 0);
      }
    __syncthreads();   // all WP (Wv) reads done -> WP becomes PT
#pragma unroll
    for (int nt = 0; nt < 8; nt++) {
      u16x4 tv;
#pragma unroll
      for (int j = 0; j < 4; j++) tv[j] = f2bf(acc[nt][j]);
      *(u16x4*)((char*)VTs + swz7((nt * 16 + lrow) * 128 + (wid * 16 + lg * 4) * 2)) = tv;
    }
  }
  __syncthreads();     // Qs, Ks, VTs visible to all waves

  // ---- attention: wave handles 2 heads ----
  char* PTw = (char*)WP + wid * 8192;
  size_t rbase = ((size_t)branch * Bb + b) * 64;
#pragma unroll 1
  for (int hi = 0; hi < 2; hi++) {
    int h = wid * 2 + hi;
    bf8v af[4], bq[4];
    if (lg < 2) {
#pragma unroll
      for (int t = 0; t < 4; t++) {
        af[t] = *(const bf8v*)((char*)Ks + swz((t * 16 + lrow) * 256 + h * 32 + lg * 16));
        bq[t] = *(const bf8v*)((char*)AQ + swz((t * 16 + lrow) * 256 + h * 32 + lg * 16));
      }
    } else {
#pragma unroll
      for (int t = 0; t < 4; t++)
#pragma unroll
        for (int i = 0; i < 8; i++) { af[t][i] = 0; bq[t][i] = 0; }
    }
#pragma unroll 1
    for (int nt = 0; nt < 4; nt++) {
      f4v sa[4];
#pragma unroll
      for (int mt = 0; mt < 4; mt++)
#pragma unroll
        for (int j = 0; j < 4; j++) sa[mt][j] = 0.f;
#pragma unroll
      for (int mt = 0; mt < 4; mt++)
        sa[mt] = __builtin_amdgcn_mfma_f32_16x16x32_bf16(af[mt], bq[nt], sa[mt], 0, 0, 0);
      float m = -3.0e38f;
#pragma unroll
      for (int mt = 0; mt < 4; mt++)
#pragma unroll
        for (int j = 0; j < 4; j++) {
          int mk = mflag[mt][j];
          float v = sa[mt][j] * 0.25f;
          v = (mk == 1) ? -1e9f : v;
          v = (mk == 2) ? -3.0e38f : v;
          sa[mt][j] = v;
          m = fmaxf(m, v);
        }
      m = fmaxf(m, __shfl_xor(m, 16, 64));
      m = fmaxf(m, __shfl_xor(m, 32, 64));
      float s = 0.f;
#pragma unroll
      for (int mt = 0; mt < 4; mt++)
#pragma unroll
        for (int j = 0; j < 4; j++) {
          float p = expf(sa[mt][j] - m);
          sa[mt][j] = p;
          s += p;
        }
      s += __shfl_xor(s, 16, 64);
      s += __shfl_xor(s, 32, 64);
      float inv = 1.f / s;
      int q = nt * 16 + lrow;
#pragma unroll
      for (int mt = 0; mt < 4; mt++) {
        u16x4 pw;
#pragma unroll
        for (int j = 0; j < 4; j++) pw[j] = f2bf(sa[mt][j] * inv);
        *(u16x4*)(PTw + swz7(q * 128 + mt * 32 + lg * 8)) = pw;
      }
    }
    // O^T = V^T @ P^T
    f4v pacc[4];
#pragma unroll
    for (int nt = 0; nt < 4; nt++)
#pragma unroll
      for (int j = 0; j < 4; j++) pacc[nt][j] = 0.f;
#pragma unroll
    for (int kt = 0; kt < 2; kt++) {
      bf8v av = *(const bf8v*)((char*)VTs + swz7((h * 16 + lrow) * 128 + kt * 64 + lg * 16));
#pragma unroll
      for (int nt = 0; nt < 4; nt++) {
        bf8v bv = *(const bf8v*)(PTw + swz7((nt * 16 + lrow) * 128 + kt * 64 + lg * 16));
        pacc[nt] = __builtin_amdgcn_mfma_f32_16x16x32_bf16(av, bv, pacc[nt], 0, 0, 0);
      }
    }
#pragma unroll
    for (int nt = 0; nt < 4; nt++) {
      int q = nt * 16 + lrow;
      unsigned* cp = (unsigned*)(ctxp + (rbase + q) * Dd + h * 16 + lg * 4);
      cp[0] = (unsigned)f2bf(pacc[nt][0]) | ((unsigned)f2bf(pacc[nt][1]) << 16);
      cp[1] = (unsigned)f2bf(pacc[nt][2]) | ((unsigned)f2bf(pacc[nt][3]) << 16);
    }
  }
}

// ---------------- MFMA GEMM + residual + LayerNorm (padded ctx in) --------------
__global__ __launch_bounds__(256) void k_gemm_ln(
    const unsigned short* __restrict__ ctxp,
    const unsigned short* __restrict__ hidT, const unsigned short* __restrict__ hidS,
    const unsigned short* __restrict__ WTbase,
    const float* __restrict__ tg, const float* __restrict__ tb,
    const float* __restrict__ sg, const float* __restrict__ sb_,
    unsigned short* __restrict__ attall) {
  __shared__ unsigned short WT[Dd * Dd];
  __shared__ __align__(16) char UB[64 * 132 * 4];
  unsigned short* Ab = (unsigned short*)UB;
  float (*O)[132] = (float (*)[132])UB;

  int b = blockIdx.x & 511, branch = blockIdx.x >> 9;
  const unsigned short* resid = (branch ? hidS : hidT);
  const unsigned short* Wg = WTbase + (size_t)(5 + branch * 4) * Dd * Dd;
  const float* lng = branch ? sg : tg;
  const float* lnb = branch ? sb_ : tb;
  unsigned short* out = attall + (size_t)branch * BL * Dd;
  int tid = threadIdx.x;

  {
    const u16x8* src = (const u16x8*)Wg;
    for (int u = tid; u < 2048; u += 256)
      *(u16x8*)((char*)WT + swz(u * 16)) = src[u];
  }
  for (int u = tid; u < 1024; u += 256) {
    int rr = u >> 4;
    u16x8 pv = ((const u16x8*)ctxp)[(((size_t)branch * Bb + b) * 64 + rr) * 16 + (u & 15)];
    *(u16x8*)((char*)Ab + swz(rr * 256 + (u & 15) * 16)) = pv;
  }
  __syncthreads();

  int lane = tid & 63, wid = tid >> 6;
  int lrow = lane & 15, lg = lane >> 4;
  bf8v af[4];
#pragma unroll
  for (int kc = 0; kc < 4; kc++)
    af[kc] = *(const bf8v*)((char*)Ab + swz((wid * 16 + lrow) * 256 + kc * 64 + lg * 16));
  f4v acc[8];
#pragma unroll
  for (int nt = 0; nt < 8; nt++)
#pragma unroll
    for (int j = 0; j < 4; j++) acc[nt][j] = 0.f;
#pragma unroll
  for (int nt = 0; nt < 8; nt++)
#pragma unroll
    for (int kc = 0; kc < 4; kc++) {
      bf8v bfg = *(const bf8v*)((char*)WT + swz((nt * 16 + lrow) * 256 + kc * 64 + lg * 16));
      acc[nt] = __builtin_amdgcn_mfma_f32_16x16x32_bf16(af[kc], bfg, acc[nt], 0, 0, 0);
    }
  __syncthreads();
#pragma unroll
  for (int nt = 0; nt < 8; nt++)
#pragma unroll
    for (int j = 0; j < 4; j++)
      O[wid * 16 + lg * 4 + j][nt * 16 + lrow] = acc[nt][j];
  __syncthreads();
  int r = tid >> 2, c0 = (tid & 3) * 32;
  if (r < Ll) {
    size_t gr = (size_t)b * Ll + r;
    float vv[32];
    float s1 = 0.f, s2 = 0.f;
#pragma unroll
    for (int i8 = 0; i8 < 4; i8++) {
      u16x8 hb = *(const u16x8*)(resid + gr * Dd + c0 + i8 * 8);
#pragma unroll
      for (int i = 0; i < 8; i++) {
        float x = O[r][c0 + i8 * 8 + i] + bf2f(hb[i]);
        vv[i8 * 8 + i] = x; s1 += x; s2 += x * x;
      }
    }
    s1 += __shfl_xor(s1, 1, 64); s2 += __shfl_xor(s2, 1, 64);
    s1 += __shfl_xor(s1, 2, 64); s2 += __shfl_xor(s2, 2, 64);
    float mu = s1 * (1.f / Dd);
    float var = s2 * (1.f / Dd) - mu * mu;
    float rs = rsqrtf(var + 1e-6f);
#pragma unroll
    for (int i8 = 0; i8 < 4; i8++) {
      u16x8 ov;
#pragma unroll
      for (int i = 0; i < 8; i++) {
        int c = c0 + i8 * 8 + i;
        ov[i] = f2bf((vv[i8 * 8 + i] - mu) * rs * lng[c] + lnb[c]);
      }
      *(u16x8*)(out + gr * Dd + c0 + i8 * 8) = ov;
    }
  }
}

// ---------------- edge gather ----------------
__global__ __launch_bounds__(256) void k_gather_e(const unsigned short* __restrict__ X,
                                                  const int* __restrict__ seq,
                                                  unsigned short* __restrict__ EDGE) {
  int r = blockIdx.x * 16 + (threadIdx.x >> 4);
  int c0 = (threadIdx.x & 15) * 8;
  const int* row = seq + (size_t)r * Ll;
  float acc[8];
#pragma unroll
  for (int i = 0; i < 8; i++) acc[i] = 0.f;
  int cnt = 0;
#pragma unroll 1
  for (int l0 = 0; l0 < Ll; l0 += 10) {
    int ids[10];
#pragma unroll
    for (int t = 0; t < 10; t++) ids[t] = row[l0 + t];
    u16x8 vv[10];
#pragma unroll
    for (int t = 0; t < 10; t++)
      vv[t] = *(const u16x8*)(X + (size_t)ids[t] * Dd + c0);
#pragma unroll
    for (int t = 0; t < 10; t++)
      if (ids[t] > 0) {
        cnt++;
#pragma unroll
        for (int i = 0; i < 8; i++) acc[i] += bf2f(vv[t][i]);
      }
  }
  u16x8 ov;
  if (cnt) {
    float inv = 1.f / (float)cnt;
#pragma unroll
    for (int i = 0; i < 8; i++) ov[i] = f2bf(fmaxf(acc[i] * inv, 0.f));
  } else {
    u16x8 x0 = *(const u16x8*)(X + c0);
#pragma unroll
    for (int i = 0; i < 8; i++) ov[i] = f2bf(fmaxf(bf2f(x0[i]), 0.f));
  }
  *(u16x8*)(EDGE + (size_t)r * Dd + c0) = ov;
}

// ---------------- fused node-gather + hidden build ----------------
__global__ __launch_bounds__(256) void k_hidfuse(
    const unsigned short* __restrict__ E1, const int* __restrict__ data_idx,
    const int* __restrict__ seq, const int* __restrict__ tsmp,
    const int* __restrict__ uinf, const int* __restrict__ ulev,
    const int* __restrict__ useq,
    const float* __restrict__ time_emb, const float* __restrict__ inf_emb,
    const float* __restrict__ pos_emb,
    unsigned short* __restrict__ hidTb, unsigned short* __restrict__ hidSb) {
  int bl = blockIdx.x * 16 + (threadIdx.x >> 4);
  int c0 = (threadIdx.x & 15) * 8;
  int b = bl / Ll, l = bl % Ll;
  int e = data_idx[b];
  int sid = seq[(size_t)e * Ll + l];
  const int* urow = useq + (size_t)sid * LuU;
  float acc[8];
#pragma unroll
  for (int i = 0; i < 8; i++) acc[i] = 0.f;
  int cnt = 0;
#pragma unroll 1
  for (int t0 = 0; t0 < LuU; t0 += 10) {
    int ids[10];
#pragma unroll
    for (int t = 0; t < 10; t++) ids[t] = urow[t0 + t];
    u16x8 vv[10];
#pragma unroll
    for (int t = 0; t < 10; t++)
      vv[t] = *(const u16x8*)(E1 + (size_t)ids[t] * Dd + c0);
#pragma unroll
    for (int t = 0; t < 10; t++)
      if (ids[t] > 0) {
        cnt++;
#pragma unroll
        for (int i = 0; i < 8; i++) acc[i] += bf2f(vv[t][i]);
      }
  }
  float node[8];
  if (cnt) {
    float inv = 1.f / (float)cnt;
#pragma unroll
    for (int i = 0; i < 8; i++) node[i] = acc[i] * inv;
  } else {
    u16x8 e0 = *(const u16x8*)(E1 + c0);
#pragma unroll
    for (int i = 0; i < 8; i++) node[i] = bf2f(e0[i]);
  }
  int ts = tsmp[(size_t)e * Ll + l];
  int fi = uinf[(size_t)e * Ll + l];
  int lv = ulev[(size_t)e * Ll + l];
  const float4* tp = (const float4*)(time_emb + (size_t)ts * Dd + c0);
  const float4* ip = (const float4*)(inf_emb + (size_t)fi * Dd + c0);
  const float4* pp = (const float4*)(pos_emb + (size_t)lv * Dd + c0);
  float4 t0 = tp[0], t1 = tp[1];
  float4 i0 = ip[0], i1 = ip[1];
  float4 p0 = pp[0], p1 = pp[1];
  float te[8] = {t0.x, t0.y, t0.z, t0.w, t1.x, t1.y, t1.z, t1.w};
  float ie[8] = {i0.x, i0.y, i0.z, i0.w, i1.x, i1.y, i1.z, i1.w};
  float pe[8] = {p0.x, p0.y, p0.z, p0.w, p1.x, p1.y, p1.z, p1.w};
  u16x8 ht, hs;
#pragma unroll
  for (int i = 0; i < 8; i++) {
    ht[i] = f2bf(node[i] + te[i]);
    hs[i] = f2bf(node[i] + ie[i] + pe[i]);
  }
  size_t o = (size_t)bl * Dd + c0;
  *(u16x8*)(hidTb + o) = ht;
  *(u16x8*)(hidSb + o) = hs;
}

// ---------------- news weighted reduce ----------------
__global__ __launch_bounds__(128) void k_newsred(const unsigned short* __restrict__ attall,
                                                 const int* __restrict__ data_idx,
                                                 const int* __restrict__ seq,
                                                 const float* __restrict__ spread,
                                                 float* __restrict__ news) {
  __shared__ int sl[Ll];
  __shared__ int scnt;
  int b = blockIdx.x, branch = blockIdx.y;
  int e = data_idx[b];
  const unsigned short* att = attall + (size_t)branch * BL * Dd;
  if (threadIdx.x < Ll) sl[threadIdx.x] = seq[(size_t)e * Ll + threadIdx.x];
  __syncthreads();
  if (threadIdx.x == 0) {
    int c = 0;
    for (int l = 0; l < Ll; l++) c += (sl[l] > 0);
    scnt = c;
  }
  __syncthreads();
  int cnt = scnt;
  float wnp = cnt ? 1.f / (float)cnt : 0.02f;
  int c = threadIdx.x;
  float acc = 0.f;
  for (int l = 0; l < Ll; l++) {
    float w = cnt ? ((sl[l] > 0) ? wnp : 0.f) : wnp;
    acc += w * bf2f(att[((size_t)b * Ll + l) * Dd + c]);
  }
  float* nrow = news + ((size_t)branch * Bb + b) * 132;
  nrow[c] = acc;
  if (c < 2) {
    nrow[Dd + c] = branch ? spread[(size_t)e * 4 + c]
                          : spread[(size_t)e * 4 + 2 + c] * (1.f / 86400.f);
  }
}

// ---------------- news @ W ----------------
__global__ __launch_bounds__(256) void k_newsW(const float* __restrict__ news,
                                               const float* __restrict__ Wm,
                                               const float* __restrict__ W2m,
                                               float* __restrict__ NT,
                                               float* __restrict__ NS) {
  __shared__ float Wl[Dw][Dw + 1];
  __shared__ float nrow[132];
  int branch = blockIdx.y;
  const float* W = branch ? W2m : Wm;
  float* out = branch ? NS : NT;
  for (int u = threadIdx.x; u < Dw * Dw; u += 256)
    Wl[u / Dw][u % Dw] = W[u];
  for (int rr = 0; rr < 32; rr++) {
    int b = blockIdx.x * 32 + rr;
    __syncthreads();
    if (threadIdx.x < Dw)
      nrow[threadIdx.x] = news[((size_t)branch * Bb + b) * 132 + threadIdx.x];
    __syncthreads();
    int j = threadIdx.x;
    if (j < Dw) {
      float acc = 0.f;
      for (int kk = 0; kk < Dw; kk++) acc += nrow[kk] * Wl[kk][j];
      out[(size_t)b * Dw + j] = acc;
    }
  }
}

// ---------------- gated fusion + classifier + log_softmax ----------------
__global__ __launch_bounds__(256) void k_fusion(const float* __restrict__ nt,
                                                const float* __restrict__ ns,
                                                const float* __restrict__ l1w,
                                                const float* __restrict__ l1b,
                                                const float* __restrict__ l2w,
                                                const float* __restrict__ l2b,
                                                const float* __restrict__ linw,
                                                const float* __restrict__ linb,
                                                float* __restrict__ out) {
  __shared__ float rt[Dw], rs[Dw];
  __shared__ float scr[4];
  int b = blockIdx.x, j = threadIdx.x;
  if (j < Dw) { rt[j] = nt[(size_t)b * Dw + j]; rs[j] = ns[(size_t)b * Dw + j]; }
  __syncthreads();
  float pt = 0.f, ps = 0.f;
  if (j < Dw) {
    float at = l1b[j], as = l1b[j];
    for (int kk = 0; kk < Dw; kk++) {
      float w = l1w[(size_t)kk * Dw + j];
      at += rt[kk] * w;
      as += rs[kk] * w;
    }
    float lw2 = l2w[j];
    pt = tanhf(at) * lw2;
    ps = tanhf(as) * lw2;
  }
  float st = block_sum_256(pt, scr);
  float ss = block_sum_256(ps, scr);
  st += l2b[0]; ss += l2b[0];
  float m = fmaxf(st, ss);
  float e0 = expf(st - m), e1v = expf(ss - m);
  float inv = 1.f / (e0 + e1v);
  float s0 = e0 * inv, s1 = e1v * inv;
  float fj  = (j < Dw) ? (s0 * rt[j] + s1 * rs[j]) : 0.f;
  float w0  = (j < Dw) ? linw[(size_t)j * 2 + 0] : 0.f;
  float w1v = (j < Dw) ? linw[(size_t)j * 2 + 1] : 0.f;
  float l0 = block_sum_256(fj * w0, scr);
  float l1 = block_sum_256(fj * w1v, scr);
  if (j == 0) {
    l0 += linb[0]; l1 += linb[1];
    float mm = fmaxf(l0, l1);
    float lse = mm + logf(expf(l0 - mm) + expf(l1 - mm));
    out[(size_t)b * 2 + 0] = l0 - lse;
    out[(size_t)b * 2 + 1] = l1 - lse;
  }
}

extern "C" void kernel_launch(void* const* d_in, const int* in_sizes, int n_in,
                              void* d_out, int out_size, void* d_ws, size_t ws_size,
                              hipStream_t stream) {
  const int*   data_idx = (const int*)d_in[0];
  const int*   seq      = (const int*)d_in[1];
  const int*   tsmp     = (const int*)d_in[2];
  const int*   ulev     = (const int*)d_in[3];
  const int*   useq     = (const int*)d_in[4];
  const int*   uinf     = (const int*)d_in[5];
  const int*   ucen     = (const int*)d_in[6];
  const float* spread   = (const float*)d_in[7];
  const float* user_emb = (const float*)d_in[9];
  const float* cen_emb  = (const float*)d_in[10];
  const float* time_emb = (const float*)d_in[11];
  const float* pos_emb  = (const float*)d_in[12];
  const float* inf_emb  = (const float*)d_in[13];
  const float* w1       = (const float*)d_in[14];
  const float* w2       = (const float*)d_in[15];
  const float* w3       = (const float*)d_in[16];
  const float* Wm       = (const float*)d_in[17];
  const float* W2m      = (const float*)d_in[18];
  const float* f_l1_w   = (const float*)d_in[19];
  const float* f_l1_b   = (const float*)d_in[20];
  const float* f_l2_w   = (const float*)d_in[21];
  const float* f_l2_b   = (const float*)d_in[22];
  const float* lin_w    = (const float*)d_in[23];
  const float* lin_b    = (const float*)d_in[24];
  const float* t_wq = (const float*)d_in[25];
  const float* t_wk = (const float*)d_in[26];
  const float* t_wv = (const float*)d_in[27];
  const float* t_wo = (const float*)d_in[28];
  const float* t_g  = (const float*)d_in[29];
  const float* t_b  = (const float*)d_in[30];
  const float* s_wq = (const float*)d_in[31];
  const float* s_wk = (const float*)d_in[32];
  const float* s_wv = (const float*)d_in[33];
  const float* s_wo = (const float*)d_in[34];
  const float* s_g  = (const float*)d_in[35];
  const float* s_b  = (const float*)d_in[36];

  char* ws = (char*)d_ws;
  constexpr size_t SZ_WT  = (size_t)10 * Dd * Dd * 2;
  constexpr size_t SZ_XB  = (size_t)Nn * Dd * 2;
  constexpr size_t SZ_EB  = (size_t)Ee * Dd * 2;
  constexpr size_t SZ_BH  = (size_t)BL * Dd * 2;       // unpadded bf16 [BL][128]
  constexpr size_t SZ_PD  = (size_t)2 * BLP * Dd * 2;  // padded 2-branch ctx
  constexpr size_t OFF_WT  = 8192;
  constexpr size_t OFF_X   = OFF_WT + SZ_WT;
  constexpr size_t OFF_EDGE= OFF_X + SZ_XB;
  constexpr size_t OFF_E1  = OFF_EDGE + SZ_EB;
  constexpr size_t OFF_HTB = OFF_E1 + SZ_EB;
  constexpr size_t OFF_HSB = OFF_HTB + SZ_BH;
  constexpr size_t OFF_CTX = OFF_HSB + SZ_BH;
  constexpr size_t OFF_ATT = OFF_CTX + SZ_PD;
  constexpr size_t OFF_NEWS= OFF_ATT + 2 * SZ_BH;
  constexpr size_t OFF_NT  = OFF_NEWS + (size_t)2 * Bb * 132 * 4;
  constexpr size_t OFF_NS  = OFF_NT + (size_t)Bb * Dw * 4;

  float* dotb    = (float*)(ws + 0);
  float* nrmb    = (float*)(ws + 3072);
  float* internw = (float*)(ws + 6144);
  unsigned short* WTall = (unsigned short*)(ws + OFF_WT);
  unsigned short* Xb    = (unsigned short*)(ws + OFF_X);
  unsigned short* EDGEb = (unsigned short*)(ws + OFF_EDGE);
  unsigned short* E1b   = (unsigned short*)(ws + OFF_E1);
  unsigned short* HIDTb = (unsigned short*)(ws + OFF_HTB);
  unsigned short* HIDSb = (unsigned short*)(ws + OFF_HSB);
  unsigned short* CTXp  = (unsigned short*)(ws + OFF_CTX);
  unsigned short* ATTall= (unsigned short*)(ws + OFF_ATT);
  float*          NEWS  = (float*)(ws + OFF_NEWS);
  float*          NT    = (float*)(ws + OFF_NT);
  float*          NS    = (float*)(ws + OFF_NS);
  float* outp = (float*)d_out;

  k_prep<<<80, 256, 0, stream>>>(w1, w2, t_wq, t_wk, t_wv, t_wo,
                                 s_wq, s_wk, s_wv, s_wo, WTall);
  k_cos<<<TVv, 256, 0, stream>>>(w3, dotb, nrmb);
  k_internw<<<1, 256, 0, stream>>>(dotb, nrmb, internw);

  k_gemm_plain<0><<<(Nn + 63) / 64, 256, 0, stream>>>(
      user_emb, cen_emb, ucen, internw, WTall + 0 * Dd * Dd, Xb, Nn);
  k_gather_e<<<Ee / 16, 256, 0, stream>>>(Xb, seq, EDGEb);
  k_gemm_plain<1><<<(Ee + 63) / 64, 256, 0, stream>>>(
      EDGEb, nullptr, nullptr, nullptr, WTall + 1 * Dd * Dd, E1b, Ee);
  k_hidfuse<<<BL / 16, 256, 0, stream>>>(E1b, data_idx, seq, tsmp, uinf, ulev, useq,
                                         time_emb, inf_emb, pos_emb, HIDTb, HIDSb);

  k_qkvattn<<<dim3(Bb, 2), 256, 0, stream>>>(HIDTb, HIDSb, WTall, data_idx, seq, CTXp);
  k_gemm_ln<<<1024, 256, 0, stream>>>(CTXp, HIDTb, HIDSb, WTall,
                                      t_g, t_b, s_g, s_b, ATTall);

  k_newsred<<<dim3(Bb, 2), 128, 0, stream>>>(ATTall, data_idx, seq, spread, NEWS);
  k_newsW<<<dim3(16, 2), 256, 0, stream>>>(NEWS, Wm, W2m, NT, NS);
  k_fusion<<<Bb, 256, 0, stream>>>(NT, NS, f_l1_w, f_l1_b, f_l2_w, f_l2_b,
                                   lin_w, lin_b, outp);

  (void)in_sizes; (void)n_in; (void)out_size; (void)ws_size;
}

// Round 7
// 323.580 us; speedup vs baseline: 1.1686x; 1.1311x over previous
//
#include <hip/hip_runtime.h>
#include <math.h>

constexpr int Nn = 50000;
constexpr int Ee = 10000;
constexpr int Ll = 50;
constexpr int LuU = 20;
constexpr int Dd = 128;
constexpr int Bb = 512;
constexpr int TVv = 768;
constexpr int Dw = 130;
constexpr int BL = Bb * Ll;     // 25600
constexpr int BLP = Bb * 64;    // padded rows per branch

typedef __attribute__((ext_vector_type(8))) short bf8v;
typedef __attribute__((ext_vector_type(4))) float f4v;
typedef __attribute__((ext_vector_type(8))) unsigned short u16x8;
typedef __attribute__((ext_vector_type(4))) unsigned short u16x4;

__device__ __forceinline__ unsigned short f2bf(float f) {
  union { float f; unsigned u; } v; v.f = f;
  unsigned r = v.u + 0x7FFFu + ((v.u >> 16) & 1u);
  return (unsigned short)(r >> 16);
}
__device__ __forceinline__ float bf2f(unsigned short h) {
  union { unsigned u; float f; } v; v.u = ((unsigned)h) << 16; return v.f;
}
// XOR swizzle for [rows][256B] tiles: 16B slot ^= row&7
__device__ __forceinline__ int swz(int b) { return b ^ (((b >> 8) & 7) << 4); }
// XOR swizzle for [rows][128B] tiles
__device__ __forceinline__ int swz7(int b) { return b ^ (((b >> 7) & 7) << 4); }

__device__ __forceinline__ float block_sum_256(float v, volatile float* scr) {
#pragma unroll
  for (int o = 32; o > 0; o >>= 1) v += __shfl_down(v, o, 64);
  __syncthreads();
  if ((threadIdx.x & 63) == 0) scr[threadIdx.x >> 6] = v;
  __syncthreads();
  return scr[0] + scr[1] + scr[2] + scr[3];
}

// ---------------- cosine / inter_nw ----------------
__global__ __launch_bounds__(256) void k_cos(const float* __restrict__ w3,
                                             float* __restrict__ dotb,
                                             float* __restrict__ nrmb) {
  __shared__ float scr[4];
  int i = blockIdx.x;
  const float* row = w3 + (size_t)i * TVv;
  float d = 0.f, n = 0.f;
  for (int j = threadIdx.x; j < TVv; j += 256) {
    float a = row[j];
    d += a * w3[j];
    n += a * a;
  }
  d = block_sum_256(d, scr);
  n = block_sum_256(n, scr);
  if (threadIdx.x == 0) { dotb[i] = d; nrmb[i] = n; }
}

__global__ __launch_bounds__(256) void k_internw(const float* __restrict__ dotb,
                                                 const float* __restrict__ nrmb,
                                                 float* __restrict__ internw) {
  __shared__ float scr[4];
  float n0 = sqrtf(nrmb[0]);
  float s = 0.f;
  for (int i = threadIdx.x; i < TVv; i += 256)
    s += dotb[i] / (n0 * sqrtf(nrmb[i]));
  s = block_sum_256(s, scr);
  if (threadIdx.x == 0) *internw = s / (float)TVv;
}

// ---------------- weight prep: f32 [k][n] -> bf16 [n][k] ----------------
__global__ __launch_bounds__(256) void k_prep(
    const float* w1, const float* w2,
    const float* twq, const float* twk, const float* twv, const float* two,
    const float* swq, const float* swk, const float* swv, const float* swo,
    unsigned short* __restrict__ out) {
  int wsel = blockIdx.x >> 3, part = blockIdx.x & 7;
  const float* w;
  switch (wsel) {
    case 0: w = w1; break;  case 1: w = w2; break;
    case 2: w = twq; break; case 3: w = twk; break;
    case 4: w = twv; break; case 5: w = two; break;
    case 6: w = swq; break; case 7: w = swk; break;
    case 8: w = swv; break; default: w = swo; break;
  }
  int u = part * 256 + threadIdx.x;
  int n = u >> 4, k0 = (u & 15) * 8;
  u16x8 pv;
#pragma unroll
  for (int i = 0; i < 8; i++) pv[i] = f2bf(w[(size_t)(k0 + i) * Dd + n]);
  ((u16x8*)(out + (size_t)wsel * Dd * Dd))[u] = pv;
}

// ---------------- TH = bf16(user_emb + cen_emb[ucen]) ----------------
__global__ __launch_bounds__(256) void k_th(const float* __restrict__ ue,
                                            const float* __restrict__ ce,
                                            const int* __restrict__ ucen,
                                            unsigned short* __restrict__ TH) {
  int r = blockIdx.x * 16 + (threadIdx.x >> 4);
  int c0 = (threadIdx.x & 15) * 8;
  int cen = ucen[r];
  const float4* up = (const float4*)(ue + (size_t)r * Dd + c0);
  const float4* cp = (const float4*)(ce + (size_t)cen * Dd + c0);
  float4 u0 = up[0], u1 = up[1], v0 = cp[0], v1 = cp[1];
  float a[8] = {u0.x + v0.x, u0.y + v0.y, u0.z + v0.z, u0.w + v0.w,
                u1.x + v1.x, u1.y + v1.y, u1.z + v1.z, u1.w + v1.w};
  u16x8 o;
#pragma unroll
  for (int i = 0; i < 8; i++) o[i] = f2bf(a[i]);
  *(u16x8*)(TH + (size_t)r * Dd + c0) = o;
}

// ---------------- gather-mean over seq (bf16), optional relu ----------------
template <int RELU>
__global__ __launch_bounds__(256) void k_gather(const unsigned short* __restrict__ X,
                                                const int* __restrict__ idx,
                                                unsigned short* __restrict__ out) {
  int r = blockIdx.x * 16 + (threadIdx.x >> 4);
  int c0 = (threadIdx.x & 15) * 8;
  const int* row = idx + (size_t)r * Ll;
  float acc[8];
#pragma unroll
  for (int i = 0; i < 8; i++) acc[i] = 0.f;
  int cnt = 0;
#pragma unroll 1
  for (int l0 = 0; l0 < Ll; l0 += 10) {
    int ids[10];
#pragma unroll
    for (int t = 0; t < 10; t++) ids[t] = row[l0 + t];
    u16x8 vv[10];
#pragma unroll
    for (int t = 0; t < 10; t++)
      vv[t] = *(const u16x8*)(X + (size_t)ids[t] * Dd + c0);
#pragma unroll
    for (int t = 0; t < 10; t++)
      if (ids[t] > 0) {
        cnt++;
#pragma unroll
        for (int i = 0; i < 8; i++) acc[i] += bf2f(vv[t][i]);
      }
  }
  u16x8 ov;
  if (cnt) {
    float inv = 1.f / (float)cnt;
#pragma unroll
    for (int i = 0; i < 8; i++) {
      float v = acc[i] * inv;
      if (RELU) v = fmaxf(v, 0.f);
      ov[i] = f2bf(v);
    }
  } else {
    u16x8 x0 = *(const u16x8*)(X + c0);
#pragma unroll
    for (int i = 0; i < 8; i++) {
      float v = bf2f(x0[i]);
      if (RELU) v = fmaxf(v, 0.f);
      ov[i] = f2bf(v);
    }
  }
  *(u16x8*)(out + (size_t)r * Dd + c0) = ov;
}

// ---------------- MFMA GEMM (64-row tile, bf16 in/out) ----------------
// EPI 0: none; EPI 1: v = relu(v * (*scalep))
template <int EPI>
__global__ __launch_bounds__(256) void k_gemm_plain(
    const unsigned short* __restrict__ inA, const float* __restrict__ scalep,
    const unsigned short* __restrict__ WTg,
    unsigned short* __restrict__ out, int nrows) {
  __shared__ unsigned short WT[Dd * Dd];
  __shared__ __align__(16) unsigned short Ab[64 * Dd];
  int tid = threadIdx.x;
  float sc = (EPI == 1) ? *scalep : 1.f;
  {
    const u16x8* src = (const u16x8*)WTg;
    for (int u = tid; u < 2048; u += 256)
      *(u16x8*)((char*)WT + swz(u * 16)) = src[u];
  }
  int r0 = blockIdx.x * 64;
  for (int u = tid; u < 1024; u += 256) {
    int rr = u >> 4;
    int r = r0 + rr;
    u16x8 pv;
    if (r < nrows) pv = ((const u16x8*)inA)[(size_t)r * 16 + (u & 15)];
    else {
#pragma unroll
      for (int i = 0; i < 8; i++) pv[i] = 0;
    }
    *(u16x8*)((char*)Ab + swz(rr * 256 + (u & 15) * 16)) = pv;
  }
  __syncthreads();
  int lane = tid & 63, wid = tid >> 6;
  int lrow = lane & 15, lg = lane >> 4;
  bf8v af[4];
#pragma unroll
  for (int kc = 0; kc < 4; kc++)
    af[kc] = *(const bf8v*)((char*)Ab + swz((wid * 16 + lrow) * 256 + kc * 64 + lg * 16));
  f4v acc[8];
#pragma unroll
  for (int nt = 0; nt < 8; nt++)
#pragma unroll
    for (int j = 0; j < 4; j++) acc[nt][j] = 0.f;
#pragma unroll
  for (int nt = 0; nt < 8; nt++)
#pragma unroll
    for (int kc = 0; kc < 4; kc++) {
      bf8v bfg = *(const bf8v*)((char*)WT + swz((nt * 16 + lrow) * 256 + kc * 64 + lg * 16));
      acc[nt] = __builtin_amdgcn_mfma_f32_16x16x32_bf16(af[kc], bfg, acc[nt], 0, 0, 0);
    }
#pragma unroll
  for (int nt = 0; nt < 8; nt++)
#pragma unroll
    for (int j = 0; j < 4; j++) {
      int r = r0 + wid * 16 + lg * 4 + j;
      if (r < nrows) {
        float v = acc[nt][j];
        if (EPI == 1) v = fmaxf(v * sc, 0.f);
        out[(size_t)r * Dd + nt * 16 + lrow] = f2bf(v);
      }
    }
}

// ---------------- fused node-gather + hidden build ----------------
__global__ __launch_bounds__(256) void k_hidfuse(
    const unsigned short* __restrict__ E1, const int* __restrict__ data_idx,
    const int* __restrict__ seq, const int* __restrict__ tsmp,
    const int* __restrict__ uinf, const int* __restrict__ ulev,
    const int* __restrict__ useq,
    const float* __restrict__ time_emb, const float* __restrict__ inf_emb,
    const float* __restrict__ pos_emb,
    unsigned short* __restrict__ hidTb, unsigned short* __restrict__ hidSb) {
  int bl = blockIdx.x * 16 + (threadIdx.x >> 4);
  int c0 = (threadIdx.x & 15) * 8;
  int b = bl / Ll, l = bl % Ll;
  int e = data_idx[b];
  int sid = seq[(size_t)e * Ll + l];
  const int* urow = useq + (size_t)sid * LuU;
  float acc[8];
#pragma unroll
  for (int i = 0; i < 8; i++) acc[i] = 0.f;
  int cnt = 0;
#pragma unroll 1
  for (int t0 = 0; t0 < LuU; t0 += 10) {
    int ids[10];
#pragma unroll
    for (int t = 0; t < 10; t++) ids[t] = urow[t0 + t];
    u16x8 vv[10];
#pragma unroll
    for (int t = 0; t < 10; t++)
      vv[t] = *(const u16x8*)(E1 + (size_t)ids[t] * Dd + c0);
#pragma unroll
    for (int t = 0; t < 10; t++)
      if (ids[t] > 0) {
        cnt++;
#pragma unroll
        for (int i = 0; i < 8; i++) acc[i] += bf2f(vv[t][i]);
      }
  }
  float node[8];
  if (cnt) {
    float inv = 1.f / (float)cnt;
#pragma unroll
    for (int i = 0; i < 8; i++) node[i] = acc[i] * inv;
  } else {
    u16x8 e0 = *(const u16x8*)(E1 + c0);
#pragma unroll
    for (int i = 0; i < 8; i++) node[i] = bf2f(e0[i]);
  }
  int ts = tsmp[(size_t)e * Ll + l];
  int fi = uinf[(size_t)e * Ll + l];
  int lv = ulev[(size_t)e * Ll + l];
  const float4* tp = (const float4*)(time_emb + (size_t)ts * Dd + c0);
  const float4* ip = (const float4*)(inf_emb + (size_t)fi * Dd + c0);
  const float4* pp = (const float4*)(pos_emb + (size_t)lv * Dd + c0);
  float4 t0 = tp[0], t1 = tp[1];
  float4 i0 = ip[0], i1 = ip[1];
  float4 p0 = pp[0], p1 = pp[1];
  float te[8] = {t0.x, t0.y, t0.z, t0.w, t1.x, t1.y, t1.z, t1.w};
  float ie[8] = {i0.x, i0.y, i0.z, i0.w, i1.x, i1.y, i1.z, i1.w};
  float pe[8] = {p0.x, p0.y, p0.z, p0.w, p1.x, p1.y, p1.z, p1.w};
  u16x8 ht, hs;
#pragma unroll
  for (int i = 0; i < 8; i++) {
    ht[i] = f2bf(node[i] + te[i]);
    hs[i] = f2bf(node[i] + ie[i] + pe[i]);
  }
  size_t o = (size_t)bl * Dd + c0;
  *(u16x8*)(hidTb + o) = ht;
  *(u16x8*)(hidSb + o) = hs;
}

// ---------------- fused QKV + attention v2: 48 KB LDS, one barrier ------------
// Wave w owns heads {2w,2w+1}: computes Q^T/K^T for its d-slice over ALL q
// (wave-local LDS round-trip), V for its 16 kv rows over all d (cross-wave).
// PT aliases Qs+Ks after fragment prefetch; single __syncthreads.
__global__ __launch_bounds__(256, 3) void k_qkvattn(
    const unsigned short* __restrict__ hidT, const unsigned short* __restrict__ hidS,
    const unsigned short* __restrict__ WTbase,
    const int* __restrict__ data_idx, const int* __restrict__ seq,
    unsigned short* __restrict__ ctxp) {
  __shared__ __align__(16) char LDS[49152];
  char* Qs  = LDS;             // [64 q][256B d] swz
  char* Ks  = LDS + 16384;     // [64 kv][256B d] swz
  char* VTs = LDS + 32768;     // [128 d][128B kv] swz7

  int b = blockIdx.x, branch = blockIdx.y;
  int tid = threadIdx.x, lane = tid & 63, wid = tid >> 6;
  int lrow = lane & 15, lg = lane >> 4;
  const unsigned short* hid = (branch ? hidS : hidT) + (size_t)b * Ll * Dd;
  const unsigned short* Wq = WTbase + (size_t)(2 + branch * 4) * Dd * Dd;
  const unsigned short* Wk = Wq + Dd * Dd;
  const unsigned short* Wv = Wk + Dd * Dd;

  int e = data_idx[b];
  int mi = (lane < Ll) ? (seq[(size_t)e * Ll + lane] == 0 ? 1 : 0) : 2;
  int mflag[4][4];
#pragma unroll
  for (int mt = 0; mt < 4; mt++)
#pragma unroll
    for (int j = 0; j < 4; j++)
      mflag[mt][j] = __shfl(mi, mt * 16 + lg * 4 + j, 64);

  // HID fragments: all 64 q rows (zero-padded), straight from global
  bf8v hf[4][4];
#pragma unroll
  for (int qt = 0; qt < 4; qt++) {
    int q = qt * 16 + lrow;
#pragma unroll
    for (int kc = 0; kc < 4; kc++) {
      bf8v v;
      if (q < Ll) v = *(const bf8v*)(hid + (size_t)q * Dd + kc * 32 + lg * 8);
      else {
#pragma unroll
        for (int i = 0; i < 8; i++) v[i] = 0;
      }
      hf[qt][kc] = v;
    }
  }

  // Q^T then K^T: d-tiles {2w,2w+1}, all q; W frags from global (L2)
#pragma unroll
  for (int sel = 0; sel < 2; sel++) {
    const unsigned short* W = sel ? Wk : Wq;
    char* Dst = sel ? Ks : Qs;
#pragma unroll
    for (int n2 = 0; n2 < 2; n2++) {
      int n = wid * 2 + n2;
      bf8v wf[4];
#pragma unroll
      for (int kc = 0; kc < 4; kc++)
        wf[kc] = *(const bf8v*)(W + (size_t)(n * 16 + lrow) * Dd + kc * 32 + lg * 8);
#pragma unroll
      for (int qt = 0; qt < 4; qt++) {
        f4v a = {0.f, 0.f, 0.f, 0.f};
#pragma unroll
        for (int kc = 0; kc < 4; kc++)
          a = __builtin_amdgcn_mfma_f32_16x16x32_bf16(wf[kc], hf[qt][kc], a, 0, 0, 0);
        u16x4 o;
#pragma unroll
        for (int j = 0; j < 4; j++) o[j] = f2bf(a[j]);
        *(u16x4*)(Dst + swz((qt * 16 + lrow) * 256 + n * 32 + lg * 8)) = o;
      }
    }
  }
  // V: wave's 16 kv rows, all d -> VTs[d][kv]
  {
    bf8v hv[4];
    int kvq = wid * 16 + lrow;
#pragma unroll
    for (int kc = 0; kc < 4; kc++) {
      bf8v v;
      if (kvq < Ll) v = *(const bf8v*)(hid + (size_t)kvq * Dd + kc * 32 + lg * 8);
      else {
#pragma unroll
        for (int i = 0; i < 8; i++) v[i] = 0;
      }
      hv[kc] = v;
    }
#pragma unroll
    for (int nt = 0; nt < 8; nt++) {
      bf8v wf[4];
#pragma unroll
      for (int kc = 0; kc < 4; kc++)
        wf[kc] = *(const bf8v*)(Wv + (size_t)(nt * 16 + lrow) * Dd + kc * 32 + lg * 8);
      f4v a = {0.f, 0.f, 0.f, 0.f};
#pragma unroll
      for (int kc = 0; kc < 4; kc++)
        a = __builtin_amdgcn_mfma_f32_16x16x32_bf16(hv[kc], wf[kc], a, 0, 0, 0);
      u16x4 o;
#pragma unroll
      for (int j = 0; j < 4; j++) o[j] = f2bf(a[j]);
      *(u16x4*)(VTs + swz7((nt * 16 + lrow) * 128 + (wid * 16 + lg * 4) * 2)) = o;
    }
  }
  // prefetch both heads' Q/K fragments (wave-local LDS; ordered by lgkmcnt)
  bf8v af[2][4], bq[2][4];
#pragma unroll
  for (int hi = 0; hi < 2; hi++) {
    int h = wid * 2 + hi;
#pragma unroll
    for (int t = 0; t < 4; t++) {
      bf8v a, q;
      if (lg < 2) {
        a = *(const bf8v*)(Ks + swz((t * 16 + lrow) * 256 + h * 32 + lg * 16));
        q = *(const bf8v*)(Qs + swz((t * 16 + lrow) * 256 + h * 32 + lg * 16));
      } else {
#pragma unroll
        for (int i = 0; i < 8; i++) { a[i] = 0; q[i] = 0; }
      }
      af[hi][t] = a; bq[hi][t] = q;
    }
  }
  __syncthreads();   // VTs visible; Qs/Ks free -> PT region

  char* PTw = LDS + wid * 8192;
  size_t rbase = ((size_t)branch * Bb + b) * 64;
#pragma unroll
  for (int hi = 0; hi < 2; hi++) {
    int h = wid * 2 + hi;
#pragma unroll
    for (int nt = 0; nt < 4; nt++) {
      f4v sa[4];
#pragma unroll
      for (int mt = 0; mt < 4; mt++)
#pragma unroll
        for (int j = 0; j < 4; j++) sa[mt][j] = 0.f;
#pragma unroll
      for (int mt = 0; mt < 4; mt++)
        sa[mt] = __builtin_amdgcn_mfma_f32_16x16x32_bf16(af[hi][mt], bq[hi][nt], sa[mt], 0, 0, 0);
      float m = -3.0e38f;
#pragma unroll
      for (int mt = 0; mt < 4; mt++)
#pragma unroll
        for (int j = 0; j < 4; j++) {
          int mk = mflag[mt][j];
          float v = sa[mt][j] * 0.25f;
          v = (mk == 1) ? -1e9f : v;
          v = (mk == 2) ? -3.0e38f : v;
          sa[mt][j] = v;
          m = fmaxf(m, v);
        }
      m = fmaxf(m, __shfl_xor(m, 16, 64));
      m = fmaxf(m, __shfl_xor(m, 32, 64));
      float s = 0.f;
#pragma unroll
      for (int mt = 0; mt < 4; mt++)
#pragma unroll
        for (int j = 0; j < 4; j++) {
          float p = expf(sa[mt][j] - m);
          sa[mt][j] = p;
          s += p;
        }
      s += __shfl_xor(s, 16, 64);
      s += __shfl_xor(s, 32, 64);
      float inv = 1.f / s;
      int q = nt * 16 + lrow;
#pragma unroll
      for (int mt = 0; mt < 4; mt++) {
        u16x4 pw;
#pragma unroll
        for (int j = 0; j < 4; j++) pw[j] = f2bf(sa[mt][j] * inv);
        *(u16x4*)(PTw + swz7(q * 128 + mt * 32 + lg * 8)) = pw;
      }
    }
    // O^T = V^T @ P^T
    f4v pacc[4];
#pragma unroll
    for (int nt = 0; nt < 4; nt++)
#pragma unroll
      for (int j = 0; j < 4; j++) pacc[nt][j] = 0.f;
#pragma unroll
    for (int kt = 0; kt < 2; kt++) {
      bf8v av = *(const bf8v*)(VTs + swz7((h * 16 + lrow) * 128 + kt * 64 + lg * 16));
#pragma unroll
      for (int nt = 0; nt < 4; nt++) {
        bf8v bv = *(const bf8v*)(PTw + swz7((nt * 16 + lrow) * 128 + kt * 64 + lg * 16));
        pacc[nt] = __builtin_amdgcn_mfma_f32_16x16x32_bf16(av, bv, pacc[nt], 0, 0, 0);
      }
    }
#pragma unroll
    for (int nt = 0; nt < 4; nt++) {
      int q = nt * 16 + lrow;
      unsigned* cp = (unsigned*)(ctxp + (rbase + q) * Dd + h * 16 + lg * 4);
      cp[0] = (unsigned)f2bf(pacc[nt][0]) | ((unsigned)f2bf(pacc[nt][1]) << 16);
      cp[1] = (unsigned)f2bf(pacc[nt][2]) | ((unsigned)f2bf(pacc[nt][3]) << 16);
    }
  }
}

// ---------- GEMM + residual + LayerNorm + fused news reduce (no ATT tensor) ----
__global__ __launch_bounds__(256) void k_gemm_lnnews(
    const unsigned short* __restrict__ ctxp,
    const unsigned short* __restrict__ hidT, const unsigned short* __restrict__ hidS,
    const unsigned short* __restrict__ WTbase,
    const float* __restrict__ tg, const float* __restrict__ tb,
    const float* __restrict__ sg, const float* __restrict__ sb_,
    const int* __restrict__ data_idx, const int* __restrict__ seq,
    const float* __restrict__ spread,
    float* __restrict__ news) {
  __shared__ unsigned short WT[Dd * Dd];
  __shared__ __align__(16) char UB[64 * 132 * 4];
  __shared__ int sl[Ll];
  __shared__ int scnt;
  unsigned short* Ab = (unsigned short*)UB;
  float (*O)[132] = (float (*)[132])UB;

  int b = blockIdx.x & 511, branch = blockIdx.x >> 9;
  const unsigned short* resid = (branch ? hidS : hidT);
  const unsigned short* Wg = WTbase + (size_t)(5 + branch * 4) * Dd * Dd;
  const float* lng = branch ? sg : tg;
  const float* lnb = branch ? sb_ : tb;
  int tid = threadIdx.x;
  int e = data_idx[b];
  if (tid < Ll) sl[tid] = seq[(size_t)e * Ll + tid];

  {
    const u16x8* src = (const u16x8*)Wg;
    for (int u = tid; u < 2048; u += 256)
      *(u16x8*)((char*)WT + swz(u * 16)) = src[u];
  }
  for (int u = tid; u < 1024; u += 256) {
    int rr = u >> 4;
    u16x8 pv = ((const u16x8*)ctxp)[(((size_t)branch * Bb + b) * 64 + rr) * 16 + (u & 15)];
    *(u16x8*)((char*)Ab + swz(rr * 256 + (u & 15) * 16)) = pv;
  }
  __syncthreads();

  int lane = tid & 63, wid = tid >> 6;
  int lrow = lane & 15, lg = lane >> 4;
  bf8v af[4];
#pragma unroll
  for (int kc = 0; kc < 4; kc++)
    af[kc] = *(const bf8v*)((char*)Ab + swz((wid * 16 + lrow) * 256 + kc * 64 + lg * 16));
  f4v acc[8];
#pragma unroll
  for (int nt = 0; nt < 8; nt++)
#pragma unroll
    for (int j = 0; j < 4; j++) acc[nt][j] = 0.f;
#pragma unroll
  for (int nt = 0; nt < 8; nt++)
#pragma unroll
    for (int kc = 0; kc < 4; kc++) {
      bf8v bfg = *(const bf8v*)((char*)WT + swz((nt * 16 + lrow) * 256 + kc * 64 + lg * 16));
      acc[nt] = __builtin_amdgcn_mfma_f32_16x16x32_bf16(af[kc], bfg, acc[nt], 0, 0, 0);
    }
  __syncthreads();
#pragma unroll
  for (int nt = 0; nt < 8; nt++)
#pragma unroll
    for (int j = 0; j < 4; j++)
      O[wid * 16 + lg * 4 + j][nt * 16 + lrow] = acc[nt][j];
  __syncthreads();
  int r = tid >> 2, c0 = (tid & 3) * 32;
  if (r < Ll) {
    size_t gr = (size_t)b * Ll + r;
    float vv[32];
    float s1 = 0.f, s2 = 0.f;
#pragma unroll
    for (int i8 = 0; i8 < 4; i8++) {
      u16x8 hb = *(const u16x8*)(resid + gr * Dd + c0 + i8 * 8);
#pragma unroll
      for (int i = 0; i < 8; i++) {
        float x = O[r][c0 + i8 * 8 + i] + bf2f(hb[i]);
        vv[i8 * 8 + i] = x; s1 += x; s2 += x * x;
      }
    }
    s1 += __shfl_xor(s1, 1, 64); s2 += __shfl_xor(s2, 1, 64);
    s1 += __shfl_xor(s1, 2, 64); s2 += __shfl_xor(s2, 2, 64);
    float mu = s1 * (1.f / Dd);
    float var = s2 * (1.f / Dd) - mu * mu;
    float rs = rsqrtf(var + 1e-6f);
#pragma unroll
    for (int i = 0; i < 32; i++) {
      int c = c0 + i;
      O[r][c] = (vv[i] - mu) * rs * lng[c] + lnb[c];   // write back LN'd value
    }
  }
  if (tid == 0) {
    int c = 0;
    for (int l = 0; l < Ll; l++) c += (sl[l] > 0);
    scnt = c;
  }
  __syncthreads();
  // weighted column reduce -> news
  float* nrow = news + ((size_t)branch * Bb + b) * 132;
  if (tid < Dd) {
    int cnt = scnt;
    float wnp = cnt ? 1.f / (float)cnt : 0.02f;
    float a = 0.f;
    for (int l = 0; l < Ll; l++) {
      float w = cnt ? ((sl[l] > 0) ? wnp : 0.f) : wnp;
      a += w * O[l][tid];
    }
    nrow[tid] = a;
  } else if (tid < Dw) {
    int cc = tid - Dd;
    nrow[tid] = branch ? spread[(size_t)e * 4 + cc]
                       : spread[(size_t)e * 4 + 2 + cc] * (1.f / 86400.f);
  }
}

// ---------------- news @ W ----------------
__global__ __launch_bounds__(256) void k_newsW(const float* __restrict__ news,
                                               const float* __restrict__ Wm,
                                               const float* __restrict__ W2m,
                                               float* __restrict__ NT,
                                               float* __restrict__ NS) {
  __shared__ float Wl[Dw][Dw + 1];
  __shared__ float nrow[132];
  int branch = blockIdx.y;
  const float* W = branch ? W2m : Wm;
  float* out = branch ? NS : NT;
  for (int u = threadIdx.x; u < Dw * Dw; u += 256)
    Wl[u / Dw][u % Dw] = W[u];
  for (int rr = 0; rr < 32; rr++) {
    int b = blockIdx.x * 32 + rr;
    __syncthreads();
    if (threadIdx.x < Dw)
      nrow[threadIdx.x] = news[((size_t)branch * Bb + b) * 132 + threadIdx.x];
    __syncthreads();
    int j = threadIdx.x;
    if (j < Dw) {
      float acc = 0.f;
      for (int kk = 0; kk < Dw; kk++) acc += nrow[kk] * Wl[kk][j];
      out[(size_t)b * Dw + j] = acc;
    }
  }
}

// ---------------- gated fusion + classifier + log_softmax ----------------
__global__ __launch_bounds__(256) void k_fusion(const float* __restrict__ nt,
                                                const float* __restrict__ ns,
                                                const float* __restrict__ l1w,
                                                const float* __restrict__ l1b,
                                                const float* __restrict__ l2w,
                                                const float* __restrict__ l2b,
                                                const float* __restrict__ linw,
                                                const float* __restrict__ linb,
                                                float* __restrict__ out) {
  __shared__ float rt[Dw], rs[Dw];
  __shared__ float scr[4];
  int b = blockIdx.x, j = threadIdx.x;
  if (j < Dw) { rt[j] = nt[(size_t)b * Dw + j]; rs[j] = ns[(size_t)b * Dw + j]; }
  __syncthreads();
  float pt = 0.f, ps = 0.f;
  if (j < Dw) {
    float at = l1b[j], as = l1b[j];
    for (int kk = 0; kk < Dw; kk++) {
      float w = l1w[(size_t)kk * Dw + j];
      at += rt[kk] * w;
      as += rs[kk] * w;
    }
    float lw2 = l2w[j];
    pt = tanhf(at) * lw2;
    ps = tanhf(as) * lw2;
  }
  float st = block_sum_256(pt, scr);
  float ss = block_sum_256(ps, scr);
  st += l2b[0]; ss += l2b[0];
  float m = fmaxf(st, ss);
  float e0 = expf(st - m), e1v = expf(ss - m);
  float inv = 1.f / (e0 + e1v);
  float s0 = e0 * inv, s1 = e1v * inv;
  float fj  = (j < Dw) ? (s0 * rt[j] + s1 * rs[j]) : 0.f;
  float w0  = (j < Dw) ? linw[(size_t)j * 2 + 0] : 0.f;
  float w1v = (j < Dw) ? linw[(size_t)j * 2 + 1] : 0.f;
  float l0 = block_sum_256(fj * w0, scr);
  float l1 = block_sum_256(fj * w1v, scr);
  if (j == 0) {
    l0 += linb[0]; l1 += linb[1];
    float mm = fmaxf(l0, l1);
    float lse = mm + logf(expf(l0 - mm) + expf(l1 - mm));
    out[(size_t)b * 2 + 0] = l0 - lse;
    out[(size_t)b * 2 + 1] = l1 - lse;
  }
}

extern "C" void kernel_launch(void* const* d_in, const int* in_sizes, int n_in,
                              void* d_out, int out_size, void* d_ws, size_t ws_size,
                              hipStream_t stream) {
  const int*   data_idx = (const int*)d_in[0];
  const int*   seq      = (const int*)d_in[1];
  const int*   tsmp     = (const int*)d_in[2];
  const int*   ulev     = (const int*)d_in[3];
  const int*   useq     = (const int*)d_in[4];
  const int*   uinf     = (const int*)d_in[5];
  const int*   ucen     = (const int*)d_in[6];
  const float* spread   = (const float*)d_in[7];
  const float* user_emb = (const float*)d_in[9];
  const float* cen_emb  = (const float*)d_in[10];
  const float* time_emb = (const float*)d_in[11];
  const float* pos_emb  = (const float*)d_in[12];
  const float* inf_emb  = (const float*)d_in[13];
  const float* w1       = (const float*)d_in[14];
  const float* w2       = (const float*)d_in[15];
  const float* w3       = (const float*)d_in[16];
  const float* Wm       = (const float*)d_in[17];
  const float* W2m      = (const float*)d_in[18];
  const float* f_l1_w   = (const float*)d_in[19];
  const float* f_l1_b   = (const float*)d_in[20];
  const float* f_l2_w   = (const float*)d_in[21];
  const float* f_l2_b   = (const float*)d_in[22];
  const float* lin_w    = (const float*)d_in[23];
  const float* lin_b    = (const float*)d_in[24];
  const float* t_wq = (const float*)d_in[25];
  const float* t_wk = (const float*)d_in[26];
  const float* t_wv = (const float*)d_in[27];
  const float* t_wo = (const float*)d_in[28];
  const float* t_g  = (const float*)d_in[29];
  const float* t_b  = (const float*)d_in[30];
  const float* s_wq = (const float*)d_in[31];
  const float* s_wk = (const float*)d_in[32];
  const float* s_wv = (const float*)d_in[33];
  const float* s_wo = (const float*)d_in[34];
  const float* s_g  = (const float*)d_in[35];
  const float* s_b  = (const float*)d_in[36];

  char* ws = (char*)d_ws;
  constexpr size_t SZ_WT  = (size_t)10 * Dd * Dd * 2;
  constexpr size_t SZ_TH  = (size_t)Nn * Dd * 2;
  constexpr size_t SZ_EB  = (size_t)Ee * Dd * 2;
  constexpr size_t SZ_BH  = (size_t)BL * Dd * 2;
  constexpr size_t SZ_PD  = (size_t)2 * BLP * Dd * 2;
  constexpr size_t OFF_WT  = 8192;
  constexpr size_t OFF_TH  = OFF_WT + SZ_WT;
  constexpr size_t OFF_G   = OFF_TH + SZ_TH;
  constexpr size_t OFF_EDGE= OFF_G + SZ_EB;
  constexpr size_t OFF_E1  = OFF_EDGE + SZ_EB;
  constexpr size_t OFF_HTB = OFF_E1 + SZ_EB;
  constexpr size_t OFF_HSB = OFF_HTB + SZ_BH;
  constexpr size_t OFF_CTX = OFF_HSB + SZ_BH;
  constexpr size_t OFF_NEWS= OFF_CTX + SZ_PD;
  constexpr size_t OFF_NT  = OFF_NEWS + (size_t)2 * Bb * 132 * 4;
  constexpr size_t OFF_NS  = OFF_NT + (size_t)Bb * Dw * 4;

  float* dotb    = (float*)(ws + 0);
  float* nrmb    = (float*)(ws + 3072);
  float* internw = (float*)(ws + 6144);
  unsigned short* WTall = (unsigned short*)(ws + OFF_WT);
  unsigned short* TH    = (unsigned short*)(ws + OFF_TH);
  unsigned short* G     = (unsigned short*)(ws + OFF_G);
  unsigned short* EDGEb = (unsigned short*)(ws + OFF_EDGE);
  unsigned short* E1b   = (unsigned short*)(ws + OFF_E1);
  unsigned short* HIDTb = (unsigned short*)(ws + OFF_HTB);
  unsigned short* HIDSb = (unsigned short*)(ws + OFF_HSB);
  unsigned short* CTXp  = (unsigned short*)(ws + OFF_CTX);
  float*          NEWS  = (float*)(ws + OFF_NEWS);
  float*          NT    = (float*)(ws + OFF_NT);
  float*          NS    = (float*)(ws + OFF_NS);
  float* outp = (float*)d_out;

  k_prep<<<80, 256, 0, stream>>>(w1, w2, t_wq, t_wk, t_wv, t_wo,
                                 s_wq, s_wk, s_wv, s_wo, WTall);
  k_cos<<<TVv, 256, 0, stream>>>(w3, dotb, nrmb);
  k_internw<<<1, 256, 0, stream>>>(dotb, nrmb, internw);

  // HGNN front-end: TH -> gather-mean -> (relu(.*nw) @ w1) -> @ w2
  k_th<<<Nn / 16, 256, 0, stream>>>(user_emb, cen_emb, ucen, TH);
  k_gather<0><<<Ee / 16, 256, 0, stream>>>(TH, seq, G);
  k_gemm_plain<1><<<(Ee + 63) / 64, 256, 0, stream>>>(
      G, internw, WTall + 0 * Dd * Dd, EDGEb, Ee);
  k_gemm_plain<0><<<(Ee + 63) / 64, 256, 0, stream>>>(
      EDGEb, nullptr, WTall + 1 * Dd * Dd, E1b, Ee);
  k_hidfuse<<<BL / 16, 256, 0, stream>>>(E1b, data_idx, seq, tsmp, uinf, ulev, useq,
                                         time_emb, inf_emb, pos_emb, HIDTb, HIDSb);

  k_qkvattn<<<dim3(Bb, 2), 256, 0, stream>>>(HIDTb, HIDSb, WTall, data_idx, seq, CTXp);
  k_gemm_lnnews<<<1024, 256, 0, stream>>>(CTXp, HIDTb, HIDSb, WTall,
                                          t_g, t_b, s_g, s_b,
                                          data_idx, seq, spread, NEWS);

  k_newsW<<<dim3(16, 2), 256, 0, stream>>>(NEWS, Wm, W2m, NT, NS);
  k_fusion<<<Bb, 256, 0, stream>>>(NT, NS, f_l1_w, f_l1_b, f_l2_w, f_l2_b,
                                   lin_w, lin_b, outp);

  (void)in_sizes; (void)n_in; (void)out_size; (void)ws_size;
}

// Round 8
// 319.928 us; speedup vs baseline: 1.1820x; 1.0114x over previous
//
#include <hip/hip_runtime.h>
#include <math.h>

constexpr int Nn = 50000;
constexpr int Ee = 10000;
constexpr int Ll = 50;
constexpr int LuU = 20;
constexpr int Dd = 128;
constexpr int Bb = 512;
constexpr int TVv = 768;
constexpr int Dw = 130;
constexpr int BL = Bb * Ll;     // 25600
constexpr int BLP = Bb * 64;    // padded rows per branch

typedef __attribute__((ext_vector_type(8))) short bf8v;
typedef __attribute__((ext_vector_type(4))) float f4v;
typedef __attribute__((ext_vector_type(8))) unsigned short u16x8;
typedef __attribute__((ext_vector_type(4))) unsigned short u16x4;

__device__ __forceinline__ unsigned short f2bf(float f) {
  union { float f; unsigned u; } v; v.f = f;
  unsigned r = v.u + 0x7FFFu + ((v.u >> 16) & 1u);
  return (unsigned short)(r >> 16);
}
__device__ __forceinline__ float bf2f(unsigned short h) {
  union { unsigned u; float f; } v; v.u = ((unsigned)h) << 16; return v.f;
}
// XOR swizzle for [rows][256B] tiles: 16B slot ^= row&7
__device__ __forceinline__ int swz(int b) { return b ^ (((b >> 8) & 7) << 4); }
// XOR swizzle for [rows][128B] tiles
__device__ __forceinline__ int swz7(int b) { return b ^ (((b >> 7) & 7) << 4); }

__device__ __forceinline__ float block_sum_256(float v, volatile float* scr) {
#pragma unroll
  for (int o = 32; o > 0; o >>= 1) v += __shfl_down(v, o, 64);
  __syncthreads();
  if ((threadIdx.x & 63) == 0) scr[threadIdx.x >> 6] = v;
  __syncthreads();
  return scr[0] + scr[1] + scr[2] + scr[3];
}

// ---------------- cosine / inter_nw ----------------
__global__ __launch_bounds__(256) void k_cos(const float* __restrict__ w3,
                                             float* __restrict__ dotb,
                                             float* __restrict__ nrmb) {
  __shared__ float scr[4];
  int i = blockIdx.x;
  const float* row = w3 + (size_t)i * TVv;
  float d = 0.f, n = 0.f;
  for (int j = threadIdx.x; j < TVv; j += 256) {
    float a = row[j];
    d += a * w3[j];
    n += a * a;
  }
  d = block_sum_256(d, scr);
  n = block_sum_256(n, scr);
  if (threadIdx.x == 0) { dotb[i] = d; nrmb[i] = n; }
}

__global__ __launch_bounds__(256) void k_internw(const float* __restrict__ dotb,
                                                 const float* __restrict__ nrmb,
                                                 float* __restrict__ internw) {
  __shared__ float scr[4];
  float n0 = sqrtf(nrmb[0]);
  float s = 0.f;
  for (int i = threadIdx.x; i < TVv; i += 256)
    s += dotb[i] / (n0 * sqrtf(nrmb[i]));
  s = block_sum_256(s, scr);
  if (threadIdx.x == 0) *internw = s / (float)TVv;
}

// ---------------- weight prep: f32 [k][n] -> bf16 [n][k] ----------------
__global__ __launch_bounds__(256) void k_prep(
    const float* w1, const float* w2,
    const float* twq, const float* twk, const float* twv, const float* two,
    const float* swq, const float* swk, const float* swv, const float* swo,
    unsigned short* __restrict__ out) {
  int wsel = blockIdx.x >> 3, part = blockIdx.x & 7;
  const float* w;
  switch (wsel) {
    case 0: w = w1; break;  case 1: w = w2; break;
    case 2: w = twq; break; case 3: w = twk; break;
    case 4: w = twv; break; case 5: w = two; break;
    case 6: w = swq; break; case 7: w = swk; break;
    case 8: w = swv; break; default: w = swo; break;
  }
  int u = part * 256 + threadIdx.x;
  int n = u >> 4, k0 = (u & 15) * 8;
  u16x8 pv;
#pragma unroll
  for (int i = 0; i < 8; i++) pv[i] = f2bf(w[(size_t)(k0 + i) * Dd + n]);
  ((u16x8*)(out + (size_t)wsel * Dd * Dd))[u] = pv;
}

// ---------------- TH = bf16(user_emb + cen_emb[ucen]) ----------------
__global__ __launch_bounds__(256) void k_th(const float* __restrict__ ue,
                                            const float* __restrict__ ce,
                                            const int* __restrict__ ucen,
                                            unsigned short* __restrict__ TH) {
  int r = blockIdx.x * 16 + (threadIdx.x >> 4);
  int c0 = (threadIdx.x & 15) * 8;
  int cen = ucen[r];
  const float4* up = (const float4*)(ue + (size_t)r * Dd + c0);
  const float4* cp = (const float4*)(ce + (size_t)cen * Dd + c0);
  float4 u0 = up[0], u1 = up[1], v0 = cp[0], v1 = cp[1];
  float a[8] = {u0.x + v0.x, u0.y + v0.y, u0.z + v0.z, u0.w + v0.w,
                u1.x + v1.x, u1.y + v1.y, u1.z + v1.z, u1.w + v1.w};
  u16x8 o;
#pragma unroll
  for (int i = 0; i < 8; i++) o[i] = f2bf(a[i]);
  *(u16x8*)(TH + (size_t)r * Dd + c0) = o;
}

// ---------------- gather-mean over seq (bf16), optional relu ----------------
template <int RELU>
__global__ __launch_bounds__(256) void k_gather(const unsigned short* __restrict__ X,
                                                const int* __restrict__ idx,
                                                unsigned short* __restrict__ out) {
  int r = blockIdx.x * 16 + (threadIdx.x >> 4);
  int c0 = (threadIdx.x & 15) * 8;
  const int* row = idx + (size_t)r * Ll;
  float acc[8];
#pragma unroll
  for (int i = 0; i < 8; i++) acc[i] = 0.f;
  int cnt = 0;
#pragma unroll 1
  for (int l0 = 0; l0 < Ll; l0 += 10) {
    int ids[10];
#pragma unroll
    for (int t = 0; t < 10; t++) ids[t] = row[l0 + t];
    u16x8 vv[10];
#pragma unroll
    for (int t = 0; t < 10; t++)
      vv[t] = *(const u16x8*)(X + (size_t)ids[t] * Dd + c0);
#pragma unroll
    for (int t = 0; t < 10; t++)
      if (ids[t] > 0) {
        cnt++;
#pragma unroll
        for (int i = 0; i < 8; i++) acc[i] += bf2f(vv[t][i]);
      }
  }
  u16x8 ov;
  if (cnt) {
    float inv = 1.f / (float)cnt;
#pragma unroll
    for (int i = 0; i < 8; i++) {
      float v = acc[i] * inv;
      if (RELU) v = fmaxf(v, 0.f);
      ov[i] = f2bf(v);
    }
  } else {
    u16x8 x0 = *(const u16x8*)(X + c0);
#pragma unroll
    for (int i = 0; i < 8; i++) {
      float v = bf2f(x0[i]);
      if (RELU) v = fmaxf(v, 0.f);
      ov[i] = f2bf(v);
    }
  }
  *(u16x8*)(out + (size_t)r * Dd + c0) = ov;
}

// ---------------- MFMA GEMM (64-row tile, bf16 in/out) ----------------
// EPI 0: none; EPI 1: v = relu(v * (*scalep))
template <int EPI>
__global__ __launch_bounds__(256) void k_gemm_plain(
    const unsigned short* __restrict__ inA, const float* __restrict__ scalep,
    const unsigned short* __restrict__ WTg,
    unsigned short* __restrict__ out, int nrows) {
  __shared__ unsigned short WT[Dd * Dd];
  __shared__ __align__(16) unsigned short Ab[64 * Dd];
  int tid = threadIdx.x;
  float sc = (EPI == 1) ? *scalep : 1.f;
  {
    const u16x8* src = (const u16x8*)WTg;
    for (int u = tid; u < 2048; u += 256)
      *(u16x8*)((char*)WT + swz(u * 16)) = src[u];
  }
  int r0 = blockIdx.x * 64;
  for (int u = tid; u < 1024; u += 256) {
    int rr = u >> 4;
    int r = r0 + rr;
    u16x8 pv;
    if (r < nrows) pv = ((const u16x8*)inA)[(size_t)r * 16 + (u & 15)];
    else {
#pragma unroll
      for (int i = 0; i < 8; i++) pv[i] = 0;
    }
    *(u16x8*)((char*)Ab + swz(rr * 256 + (u & 15) * 16)) = pv;
  }
  __syncthreads();
  int lane = tid & 63, wid = tid >> 6;
  int lrow = lane & 15, lg = lane >> 4;
  bf8v af[4];
#pragma unroll
  for (int kc = 0; kc < 4; kc++)
    af[kc] = *(const bf8v*)((char*)Ab + swz((wid * 16 + lrow) * 256 + kc * 64 + lg * 16));
  f4v acc[8];
#pragma unroll
  for (int nt = 0; nt < 8; nt++)
#pragma unroll
    for (int j = 0; j < 4; j++) acc[nt][j] = 0.f;
#pragma unroll
  for (int nt = 0; nt < 8; nt++)
#pragma unroll
    for (int kc = 0; kc < 4; kc++) {
      bf8v bfg = *(const bf8v*)((char*)WT + swz((nt * 16 + lrow) * 256 + kc * 64 + lg * 16));
      acc[nt] = __builtin_amdgcn_mfma_f32_16x16x32_bf16(af[kc], bfg, acc[nt], 0, 0, 0);
    }
#pragma unroll
  for (int nt = 0; nt < 8; nt++)
#pragma unroll
    for (int j = 0; j < 4; j++) {
      int r = r0 + wid * 16 + lg * 4 + j;
      if (r < nrows) {
        float v = acc[nt][j];
        if (EPI == 1) v = fmaxf(v * sc, 0.f);
        out[(size_t)r * Dd + nt * 16 + lrow] = f2bf(v);
      }
    }
}

// ---------------- fused node-gather + hidden build ----------------
__global__ __launch_bounds__(256) void k_hidfuse(
    const unsigned short* __restrict__ E1, const int* __restrict__ data_idx,
    const int* __restrict__ seq, const int* __restrict__ tsmp,
    const int* __restrict__ uinf, const int* __restrict__ ulev,
    const int* __restrict__ useq,
    const float* __restrict__ time_emb, const float* __restrict__ inf_emb,
    const float* __restrict__ pos_emb,
    unsigned short* __restrict__ hidTb, unsigned short* __restrict__ hidSb) {
  int bl = blockIdx.x * 16 + (threadIdx.x >> 4);
  int c0 = (threadIdx.x & 15) * 8;
  int b = bl / Ll, l = bl % Ll;
  int e = data_idx[b];
  int sid = seq[(size_t)e * Ll + l];
  const int* urow = useq + (size_t)sid * LuU;
  float acc[8];
#pragma unroll
  for (int i = 0; i < 8; i++) acc[i] = 0.f;
  int cnt = 0;
#pragma unroll 1
  for (int t0 = 0; t0 < LuU; t0 += 10) {
    int ids[10];
#pragma unroll
    for (int t = 0; t < 10; t++) ids[t] = urow[t0 + t];
    u16x8 vv[10];
#pragma unroll
    for (int t = 0; t < 10; t++)
      vv[t] = *(const u16x8*)(E1 + (size_t)ids[t] * Dd + c0);
#pragma unroll
    for (int t = 0; t < 10; t++)
      if (ids[t] > 0) {
        cnt++;
#pragma unroll
        for (int i = 0; i < 8; i++) acc[i] += bf2f(vv[t][i]);
      }
  }
  float node[8];
  if (cnt) {
    float inv = 1.f / (float)cnt;
#pragma unroll
    for (int i = 0; i < 8; i++) node[i] = acc[i] * inv;
  } else {
    u16x8 e0 = *(const u16x8*)(E1 + c0);
#pragma unroll
    for (int i = 0; i < 8; i++) node[i] = bf2f(e0[i]);
  }
  int ts = tsmp[(size_t)e * Ll + l];
  int fi = uinf[(size_t)e * Ll + l];
  int lv = ulev[(size_t)e * Ll + l];
  const float4* tp = (const float4*)(time_emb + (size_t)ts * Dd + c0);
  const float4* ip = (const float4*)(inf_emb + (size_t)fi * Dd + c0);
  const float4* pp = (const float4*)(pos_emb + (size_t)lv * Dd + c0);
  float4 t0 = tp[0], t1 = tp[1];
  float4 i0 = ip[0], i1 = ip[1];
  float4 p0 = pp[0], p1 = pp[1];
  float te[8] = {t0.x, t0.y, t0.z, t0.w, t1.x, t1.y, t1.z, t1.w};
  float ie[8] = {i0.x, i0.y, i0.z, i0.w, i1.x, i1.y, i1.z, i1.w};
  float pe[8] = {p0.x, p0.y, p0.z, p0.w, p1.x, p1.y, p1.z, p1.w};
  u16x8 ht, hs;
#pragma unroll
  for (int i = 0; i < 8; i++) {
    ht[i] = f2bf(node[i] + te[i]);
    hs[i] = f2bf(node[i] + ie[i] + pe[i]);
  }
  size_t o = (size_t)bl * Dd + c0;
  *(u16x8*)(hidTb + o) = ht;
  *(u16x8*)(hidSb + o) = hs;
}

// ------- fused QKV + attention v3: 8 waves x 1 head, zero barriers ------------
// Per wave (head h = wid): Q/K via swapped mfma into a wave-private 8KB LDS
// region ([64 q][Q 32B | K 32B], swz7); V kept in registers (pv), PV A-frag
// rebuilt via shfl; P^T aliases the wave's region after an explicit lgkmcnt.
__global__ __launch_bounds__(512, 4) void k_qkvattn(
    const unsigned short* __restrict__ hidT, const unsigned short* __restrict__ hidS,
    const unsigned short* __restrict__ WTbase,
    const int* __restrict__ data_idx, const int* __restrict__ seq,
    unsigned short* __restrict__ ctxp) {
  __shared__ __align__(16) char LDS[65536];   // 8 x 8KB wave-private
  int b = blockIdx.x, branch = blockIdx.y;
  int tid = threadIdx.x, lane = tid & 63, wid = tid >> 6;  // wid == head
  int lrow = lane & 15, lg = lane >> 4;
  const unsigned short* hid = (branch ? hidS : hidT) + (size_t)b * Ll * Dd;
  const unsigned short* Wq = WTbase + (size_t)(2 + branch * 4) * Dd * Dd;
  const unsigned short* Wk = Wq + Dd * Dd;
  const unsigned short* Wv = Wk + Dd * Dd;
  char* R = LDS + wid * 8192;
  int h = wid;

  int e = data_idx[b];
  int sv = (lane < Ll) ? seq[(size_t)e * Ll + lane] : 1;
  unsigned long long mzero = __ballot(sv == 0);  // key-mask bits (uniform)

  // hid fragments for all 64 padded q rows
  bf8v hf[4][4];
#pragma unroll
  for (int qt = 0; qt < 4; qt++) {
    int q = qt * 16 + lrow;
#pragma unroll
    for (int kc = 0; kc < 4; kc++) {
      bf8v v;
      if (q < Ll) v = *(const bf8v*)(hid + (size_t)q * Dd + kc * 32 + lg * 8);
      else {
#pragma unroll
        for (int i = 0; i < 8; i++) v[i] = 0;
      }
      hf[qt][kc] = v;
    }
  }

  // ---- Q then K (swapped): C[d (head h)][q] -> R[q][sel*32 + d*2] ----
#pragma unroll
  for (int sel = 0; sel < 2; sel++) {
    const unsigned short* W = sel ? Wk : Wq;
    bf8v wf[4];
#pragma unroll
    for (int kc = 0; kc < 4; kc++)
      wf[kc] = *(const bf8v*)(W + (size_t)(h * 16 + lrow) * Dd + kc * 32 + lg * 8);
#pragma unroll
    for (int qt = 0; qt < 4; qt++) {
      f4v a = {0.f, 0.f, 0.f, 0.f};
#pragma unroll
      for (int kc = 0; kc < 4; kc++)
        a = __builtin_amdgcn_mfma_f32_16x16x32_bf16(wf[kc], hf[qt][kc], a, 0, 0, 0);
      u16x4 o;
#pragma unroll
      for (int j = 0; j < 4; j++) o[j] = f2bf(a[j]);
      *(u16x4*)(R + swz7((qt * 16 + lrow) * 128 + sel * 32 + lg * 8)) = o;
    }
  }
  // ---- V (normal): C[kv][d (head h)] kept in registers, packed bf16 ----
  unsigned pv[4][2];
  {
    bf8v wf[4];
#pragma unroll
    for (int kc = 0; kc < 4; kc++)
      wf[kc] = *(const bf8v*)(Wv + (size_t)(h * 16 + lrow) * Dd + kc * 32 + lg * 8);
#pragma unroll
    for (int mt = 0; mt < 4; mt++) {
      f4v a = {0.f, 0.f, 0.f, 0.f};
#pragma unroll
      for (int kc = 0; kc < 4; kc++)
        a = __builtin_amdgcn_mfma_f32_16x16x32_bf16(hf[mt][kc], wf[kc], a, 0, 0, 0);
      pv[mt][0] = (unsigned)f2bf(a[0]) | ((unsigned)f2bf(a[1]) << 16);
      pv[mt][1] = (unsigned)f2bf(a[2]) | ((unsigned)f2bf(a[3]) << 16);
    }
  }
  // ---- read af (K) / bq (Q) fragments for this head ----
  bf8v af[4], bq[4];
#pragma unroll
  for (int t = 0; t < 4; t++) {
    bf8v a, q;
    if (lg < 2) {
      a = *(const bf8v*)(R + swz7((t * 16 + lrow) * 128 + 32 + lg * 16));
      q = *(const bf8v*)(R + swz7((t * 16 + lrow) * 128 + lg * 16));
    } else {
#pragma unroll
      for (int i = 0; i < 8; i++) { a[i] = 0; q[i] = 0; }
    }
    af[t] = a; bq[t] = q;
  }
  asm volatile("s_waitcnt lgkmcnt(0)" ::: "memory");  // drain reads before P overwrites R
  __builtin_amdgcn_sched_barrier(0);

  // ---- S^T + softmax + P store (P aliases R) ----
  size_t rbase = ((size_t)branch * Bb + b) * 64;
  int lg4 = lg * 4;
#pragma unroll
  for (int nt = 0; nt < 4; nt++) {
    f4v sa[4];
#pragma unroll
    for (int mt = 0; mt < 4; mt++)
#pragma unroll
      for (int j = 0; j < 4; j++) sa[mt][j] = 0.f;
#pragma unroll
    for (int mt = 0; mt < 4; mt++)
      sa[mt] = __builtin_amdgcn_mfma_f32_16x16x32_bf16(af[mt], bq[nt], sa[mt], 0, 0, 0);
    float m = -3.0e38f;
#pragma unroll
    for (int mt = 0; mt < 4; mt++)
#pragma unroll
      for (int j = 0; j < 4; j++) {
        int kk = mt * 16 + lg4 + j;
        float v = sa[mt][j] * 0.25f;
        v = ((mzero >> kk) & 1ull) ? -1e9f : v;
        if (mt == 3) v = (lg4 + j >= 2) ? -3.0e38f : v;   // kv >= 50 pad
        sa[mt][j] = v;
        m = fmaxf(m, v);
      }
    m = fmaxf(m, __shfl_xor(m, 16, 64));
    m = fmaxf(m, __shfl_xor(m, 32, 64));
    float s = 0.f;
#pragma unroll
    for (int mt = 0; mt < 4; mt++)
#pragma unroll
      for (int j = 0; j < 4; j++) {
        float p = __expf(sa[mt][j] - m);
        sa[mt][j] = p;
        s += p;
      }
    s += __shfl_xor(s, 16, 64);
    s += __shfl_xor(s, 32, 64);
    float inv = 1.f / s;
    int q = nt * 16 + lrow;
#pragma unroll
    for (int mt = 0; mt < 4; mt++) {
      u16x4 pw;
#pragma unroll
      for (int j = 0; j < 4; j++) pw[j] = f2bf(sa[mt][j] * inv);
      *(u16x4*)(R + swz7(q * 128 + mt * 32 + lg * 8)) = pw;
    }
  }
  // ---- PV: av rebuilt via shfl from pv; bv from R ----
  f4v pacc[4];
#pragma unroll
  for (int nt = 0; nt < 4; nt++)
#pragma unroll
    for (int j = 0; j < 4; j++) pacc[nt][j] = 0.f;
  int srcA = lrow + 32 * (lg & 1);
  int srcB = srcA + 16;
  bool up = (lg >> 1) & 1;
#pragma unroll
  for (int kt = 0; kt < 2; kt++) {
    unsigned p00 = __shfl((int)pv[kt * 2][0],     srcA, 64);
    unsigned p10 = __shfl((int)pv[kt * 2 + 1][0], srcA, 64);
    unsigned p01 = __shfl((int)pv[kt * 2][1],     srcA, 64);
    unsigned p11 = __shfl((int)pv[kt * 2 + 1][1], srcA, 64);
    unsigned q00 = __shfl((int)pv[kt * 2][0],     srcB, 64);
    unsigned q10 = __shfl((int)pv[kt * 2 + 1][0], srcB, 64);
    unsigned q01 = __shfl((int)pv[kt * 2][1],     srcB, 64);
    unsigned q11 = __shfl((int)pv[kt * 2 + 1][1], srcB, 64);
    union { bf8v v; unsigned d[4]; } avu;
    avu.d[0] = up ? p10 : p00;
    avu.d[1] = up ? p11 : p01;
    avu.d[2] = up ? q10 : q00;
    avu.d[3] = up ? q11 : q01;
#pragma unroll
    for (int nt = 0; nt < 4; nt++) {
      bf8v bv = *(const bf8v*)(R + swz7((nt * 16 + lrow) * 128 + kt * 64 + lg * 16));
      pacc[nt] = __builtin_amdgcn_mfma_f32_16x16x32_bf16(avu.v, bv, pacc[nt], 0, 0, 0);
    }
  }
#pragma unroll
  for (int nt = 0; nt < 4; nt++) {
    int q = nt * 16 + lrow;
    unsigned* cp = (unsigned*)(ctxp + (rbase + q) * Dd + h * 16 + lg * 4);
    cp[0] = (unsigned)f2bf(pacc[nt][0]) | ((unsigned)f2bf(pacc[nt][1]) << 16);
    cp[1] = (unsigned)f2bf(pacc[nt][2]) | ((unsigned)f2bf(pacc[nt][3]) << 16);
  }
}

// ---- GEMM + residual + LayerNorm + fused news reduce (W frags from global) ----
__global__ __launch_bounds__(256) void k_gemm_lnnews(
    const unsigned short* __restrict__ ctxp,
    const unsigned short* __restrict__ hidT, const unsigned short* __restrict__ hidS,
    const unsigned short* __restrict__ WTbase,
    const float* __restrict__ tg, const float* __restrict__ tb,
    const float* __restrict__ sg, const float* __restrict__ sb_,
    const int* __restrict__ data_idx, const int* __restrict__ seq,
    const float* __restrict__ spread,
    float* __restrict__ news) {
  __shared__ __align__(16) char UB[64 * 132 * 4];
  __shared__ int sl[Ll];
  __shared__ int scnt;
  unsigned short* Ab = (unsigned short*)UB;
  float (*O)[132] = (float (*)[132])UB;

  int b = blockIdx.x & 511, branch = blockIdx.x >> 9;
  const unsigned short* resid = (branch ? hidS : hidT);
  const unsigned short* Wg = WTbase + (size_t)(5 + branch * 4) * Dd * Dd;
  const float* lng = branch ? sg : tg;
  const float* lnb = branch ? sb_ : tb;
  int tid = threadIdx.x;
  int e = data_idx[b];
  if (tid < Ll) sl[tid] = seq[(size_t)e * Ll + tid];

  for (int u = tid; u < 1024; u += 256) {
    int rr = u >> 4;
    u16x8 pv = ((const u16x8*)ctxp)[(((size_t)branch * Bb + b) * 64 + rr) * 16 + (u & 15)];
    *(u16x8*)((char*)Ab + swz(rr * 256 + (u & 15) * 16)) = pv;
  }
  __syncthreads();

  int lane = tid & 63, wid = tid >> 6;
  int lrow = lane & 15, lg = lane >> 4;
  bf8v af[4];
#pragma unroll
  for (int kc = 0; kc < 4; kc++)
    af[kc] = *(const bf8v*)((char*)Ab + swz((wid * 16 + lrow) * 256 + kc * 64 + lg * 16));
  f4v acc[8];
#pragma unroll
  for (int nt = 0; nt < 8; nt++)
#pragma unroll
    for (int j = 0; j < 4; j++) acc[nt][j] = 0.f;
#pragma unroll
  for (int nt = 0; nt < 8; nt++) {
    bf8v wf[4];
#pragma unroll
    for (int kc = 0; kc < 4; kc++)
      wf[kc] = *(const bf8v*)(Wg + (size_t)(nt * 16 + lrow) * Dd + kc * 32 + lg * 8);
#pragma unroll
    for (int kc = 0; kc < 4; kc++)
      acc[nt] = __builtin_amdgcn_mfma_f32_16x16x32_bf16(af[kc], wf[kc], acc[nt], 0, 0, 0);
  }
  __syncthreads();
#pragma unroll
  for (int nt = 0; nt < 8; nt++)
#pragma unroll
    for (int j = 0; j < 4; j++)
      O[wid * 16 + lg * 4 + j][nt * 16 + lrow] = acc[nt][j];
  __syncthreads();
  int r = tid >> 2, c0 = (tid & 3) * 32;
  if (r < Ll) {
    size_t gr = (size_t)b * Ll + r;
    float vv[32];
    float s1 = 0.f, s2 = 0.f;
#pragma unroll
    for (int i8 = 0; i8 < 4; i8++) {
      u16x8 hb = *(const u16x8*)(resid + gr * Dd + c0 + i8 * 8);
#pragma unroll
      for (int i = 0; i < 8; i++) {
        float x = O[r][c0 + i8 * 8 + i] + bf2f(hb[i]);
        vv[i8 * 8 + i] = x; s1 += x; s2 += x * x;
      }
    }
    s1 += __shfl_xor(s1, 1, 64); s2 += __shfl_xor(s2, 1, 64);
    s1 += __shfl_xor(s1, 2, 64); s2 += __shfl_xor(s2, 2, 64);
    float mu = s1 * (1.f / Dd);
    float var = s2 * (1.f / Dd) - mu * mu;
    float rs = rsqrtf(var + 1e-6f);
#pragma unroll
    for (int i = 0; i < 32; i++) {
      int c = c0 + i;
      O[r][c] = (vv[i] - mu) * rs * lng[c] + lnb[c];
    }
  }
  if (tid == 0) {
    int c = 0;
    for (int l = 0; l < Ll; l++) c += (sl[l] > 0);
    scnt = c;
  }
  __syncthreads();
  float* nrow = news + ((size_t)branch * Bb + b) * 132;
  if (tid < Dd) {
    int cnt = scnt;
    float wnp = cnt ? 1.f / (float)cnt : 0.02f;
    float a = 0.f;
    for (int l = 0; l < Ll; l++) {
      float w = cnt ? ((sl[l] > 0) ? wnp : 0.f) : wnp;
      a += w * O[l][tid];
    }
    nrow[tid] = a;
  } else if (tid < Dw) {
    int cc = tid - Dd;
    nrow[tid] = branch ? spread[(size_t)e * 4 + cc]
                       : spread[(size_t)e * 4 + 2 + cc] * (1.f / 86400.f);
  }
}

// ---------------- news @ W ----------------
__global__ __launch_bounds__(256) void k_newsW(const float* __restrict__ news,
                                               const float* __restrict__ Wm,
                                               const float* __restrict__ W2m,
                                               float* __restrict__ NT,
                                               float* __restrict__ NS) {
  __shared__ float Wl[Dw][Dw + 1];
  __shared__ float nrow[132];
  int branch = blockIdx.y;
  const float* W = branch ? W2m : Wm;
  float* out = branch ? NS : NT;
  for (int u = threadIdx.x; u < Dw * Dw; u += 256)
    Wl[u / Dw][u % Dw] = W[u];
  for (int rr = 0; rr < 32; rr++) {
    int b = blockIdx.x * 32 + rr;
    __syncthreads();
    if (threadIdx.x < Dw)
      nrow[threadIdx.x] = news[((size_t)branch * Bb + b) * 132 + threadIdx.x];
    __syncthreads();
    int j = threadIdx.x;
    if (j < Dw) {
      float acc = 0.f;
      for (int kk = 0; kk < Dw; kk++) acc += nrow[kk] * Wl[kk][j];
      out[(size_t)b * Dw + j] = acc;
    }
  }
}

// ---------------- gated fusion + classifier + log_softmax ----------------
__global__ __launch_bounds__(256) void k_fusion(const float* __restrict__ nt,
                                                const float* __restrict__ ns,
                                                const float* __restrict__ l1w,
                                                const float* __restrict__ l1b,
                                                const float* __restrict__ l2w,
                                                const float* __restrict__ l2b,
                                                const float* __restrict__ linw,
                                                const float* __restrict__ linb,
                                                float* __restrict__ out) {
  __shared__ float rt[Dw], rs[Dw];
  __shared__ float scr[4];
  int b = blockIdx.x, j = threadIdx.x;
  if (j < Dw) { rt[j] = nt[(size_t)b * Dw + j]; rs[j] = ns[(size_t)b * Dw + j]; }
  __syncthreads();
  float pt = 0.f, ps = 0.f;
  if (j < Dw) {
    float at = l1b[j], as = l1b[j];
    for (int kk = 0; kk < Dw; kk++) {
      float w = l1w[(size_t)kk * Dw + j];
      at += rt[kk] * w;
      as += rs[kk] * w;
    }
    float lw2 = l2w[j];
    pt = tanhf(at) * lw2;
    ps = tanhf(as) * lw2;
  }
  float st = block_sum_256(pt, scr);
  float ss = block_sum_256(ps, scr);
  st += l2b[0]; ss += l2b[0];
  float m = fmaxf(st, ss);
  float e0 = expf(st - m), e1v = expf(ss - m);
  float inv = 1.f / (e0 + e1v);
  float s0 = e0 * inv, s1 = e1v * inv;
  float fj  = (j < Dw) ? (s0 * rt[j] + s1 * rs[j]) : 0.f;
  float w0  = (j < Dw) ? linw[(size_t)j * 2 + 0] : 0.f;
  float w1v = (j < Dw) ? linw[(size_t)j * 2 + 1] : 0.f;
  float l0 = block_sum_256(fj * w0, scr);
  float l1 = block_sum_256(fj * w1v, scr);
  if (j == 0) {
    l0 += linb[0]; l1 += linb[1];
    float mm = fmaxf(l0, l1);
    float lse = mm + logf(expf(l0 - mm) + expf(l1 - mm));
    out[(size_t)b * 2 + 0] = l0 - lse;
    out[(size_t)b * 2 + 1] = l1 - lse;
  }
}

extern "C" void kernel_launch(void* const* d_in, const int* in_sizes, int n_in,
                              void* d_out, int out_size, void* d_ws, size_t ws_size,
                              hipStream_t stream) {
  const int*   data_idx = (const int*)d_in[0];
  const int*   seq      = (const int*)d_in[1];
  const int*   tsmp     = (const int*)d_in[2];
  const int*   ulev     = (const int*)d_in[3];
  const int*   useq     = (const int*)d_in[4];
  const int*   uinf     = (const int*)d_in[5];
  const int*   ucen     = (const int*)d_in[6];
  const float* spread   = (const float*)d_in[7];
  const float* user_emb = (const float*)d_in[9];
  const float* cen_emb  = (const float*)d_in[10];
  const float* time_emb = (const float*)d_in[11];
  const float* pos_emb  = (const float*)d_in[12];
  const float* inf_emb  = (const float*)d_in[13];
  const float* w1       = (const float*)d_in[14];
  const float* w2       = (const float*)d_in[15];
  const float* w3       = (const float*)d_in[16];
  const float* Wm       = (const float*)d_in[17];
  const float* W2m      = (const float*)d_in[18];
  const float* f_l1_w   = (const float*)d_in[19];
  const float* f_l1_b   = (const float*)d_in[20];
  const float* f_l2_w   = (const float*)d_in[21];
  const float* f_l2_b   = (const float*)d_in[22];
  const float* lin_w    = (const float*)d_in[23];
  const float* lin_b    = (const float*)d_in[24];
  const float* t_wq = (const float*)d_in[25];
  const float* t_wk = (const float*)d_in[26];
  const float* t_wv = (const float*)d_in[27];
  const float* t_wo = (const float*)d_in[28];
  const float* t_g  = (const float*)d_in[29];
  const float* t_b  = (const float*)d_in[30];
  const float* s_wq = (const float*)d_in[31];
  const float* s_wk = (const float*)d_in[32];
  const float* s_wv = (const float*)d_in[33];
  const float* s_wo = (const float*)d_in[34];
  const float* s_g  = (const float*)d_in[35];
  const float* s_b  = (const float*)d_in[36];

  char* ws = (char*)d_ws;
  constexpr size_t SZ_WT  = (size_t)10 * Dd * Dd * 2;
  constexpr size_t SZ_TH  = (size_t)Nn * Dd * 2;
  constexpr size_t SZ_EB  = (size_t)Ee * Dd * 2;
  constexpr size_t SZ_BH  = (size_t)BL * Dd * 2;
  constexpr size_t SZ_PD  = (size_t)2 * BLP * Dd * 2;
  constexpr size_t OFF_WT  = 8192;
  constexpr size_t OFF_TH  = OFF_WT + SZ_WT;
  constexpr size_t OFF_G   = OFF_TH + SZ_TH;
  constexpr size_t OFF_EDGE= OFF_G + SZ_EB;
  constexpr size_t OFF_E1  = OFF_EDGE + SZ_EB;
  constexpr size_t OFF_HTB = OFF_E1 + SZ_EB;
  constexpr size_t OFF_HSB = OFF_HTB + SZ_BH;
  constexpr size_t OFF_CTX = OFF_HSB + SZ_BH;
  constexpr size_t OFF_NEWS= OFF_CTX + SZ_PD;
  constexpr size_t OFF_NT  = OFF_NEWS + (size_t)2 * Bb * 132 * 4;
  constexpr size_t OFF_NS  = OFF_NT + (size_t)Bb * Dw * 4;

  float* dotb    = (float*)(ws + 0);
  float* nrmb    = (float*)(ws + 3072);
  float* internw = (float*)(ws + 6144);
  unsigned short* WTall = (unsigned short*)(ws + OFF_WT);
  unsigned short* TH    = (unsigned short*)(ws + OFF_TH);
  unsigned short* G     = (unsigned short*)(ws + OFF_G);
  unsigned short* EDGEb = (unsigned short*)(ws + OFF_EDGE);
  unsigned short* E1b   = (unsigned short*)(ws + OFF_E1);
  unsigned short* HIDTb = (unsigned short*)(ws + OFF_HTB);
  unsigned short* HIDSb = (unsigned short*)(ws + OFF_HSB);
  unsigned short* CTXp  = (unsigned short*)(ws + OFF_CTX);
  float*          NEWS  = (float*)(ws + OFF_NEWS);
  float*          NT    = (float*)(ws + OFF_NT);
  float*          NS    = (float*)(ws + OFF_NS);
  float* outp = (float*)d_out;

  k_prep<<<80, 256, 0, stream>>>(w1, w2, t_wq, t_wk, t_wv, t_wo,
                                 s_wq, s_wk, s_wv, s_wo, WTall);
  k_cos<<<TVv, 256, 0, stream>>>(w3, dotb, nrmb);
  k_internw<<<1, 256, 0, stream>>>(dotb, nrmb, internw);

  // HGNN front-end: TH -> gather-mean -> (relu(.*nw) @ w1) -> @ w2
  k_th<<<Nn / 16, 256, 0, stream>>>(user_emb, cen_emb, ucen, TH);
  k_gather<0><<<Ee / 16, 256, 0, stream>>>(TH, seq, G);
  k_gemm_plain<1><<<(Ee + 63) / 64, 256, 0, stream>>>(
      G, internw, WTall + 0 * Dd * Dd, EDGEb, Ee);
  k_gemm_plain<0><<<(Ee + 63) / 64, 256, 0, stream>>>(
      EDGEb, nullptr, WTall + 1 * Dd * Dd, E1b, Ee);
  k_hidfuse<<<BL / 16, 256, 0, stream>>>(E1b, data_idx, seq, tsmp, uinf, ulev, useq,
                                         time_emb, inf_emb, pos_emb, HIDTb, HIDSb);

  k_qkvattn<<<dim3(Bb, 2), 512, 0, stream>>>(HIDTb, HIDSb, WTall, data_idx, seq, CTXp);
  k_gemm_lnnews<<<1024, 256, 0, stream>>>(CTXp, HIDTb, HIDSb, WTall,
                                          t_g, t_b, s_g, s_b,
                                          data_idx, seq, spread, NEWS);

  k_newsW<<<dim3(16, 2), 256, 0, stream>>>(NEWS, Wm, W2m, NT, NS);
  k_fusion<<<Bb, 256, 0, stream>>>(NT, NS, f_l1_w, f_l1_b, f_l2_w, f_l2_b,
                                   lin_w, lin_b, outp);

  (void)in_sizes; (void)n_in; (void)out_size; (void)ws_size;
}